// Round 7
// baseline (3195.071 us; speedup 1.0000x reference)
//
#include <hip/hip_runtime.h>
#include <hip/hip_bf16.h>

// SymbolicEncoder: conv(3->64,s2)+BN+ReLU -> conv(64->128,s2)+BN+ReLU ->
// conv(128->256,s2)+BN+ReLU -> 1x1 conv(256->64, PADDED (1,1)!) -> VQ.
// KEY (decoded R0-R6): the 1x1 conv inherits padding (1,1) => z is
// (32,64,34,34); N = 36992 px; border px (h or w in {0,33}) have z = bq = 0.
// Output layout (fp32 flat): symbols (32,64,34,34) @ [0:2367488],
// loss @ 2367488, perplexity @ 2367489.

#define BATCH 32
#define QB 8   // quarter-batch

// ---------------- workspace layout (bytes, all fp32) ----------------
// statd double[1537] @0 ; sscale float[1536] @16384 ; counts int[512] @24576 ;
// csqf float[512] @28672 ; csqd double[512] @30720 ; kborder int @34816
// h1q  8x64x128x128 f32 = 33554432 B @ 262144
// y2q  8x128x64x64  f32 = 16777216 B @ 33816576
// y3   32x256x32x32 f32 = 33554432 B @ 50593792
// z    32768x64     f32 =  8388608 B @ 84148224   (end 92536832)
static const unsigned long long H1Q_OFF = 262144ull;
static const unsigned long long Y2Q_OFF = 33816576ull;
static const unsigned long long Y3_OFF  = 50593792ull;
static const unsigned long long Z_OFF   = 84148224ull;
static const unsigned long long WS_NEED = 92536832ull;

#define SYM_N 2367488      // 32*64*34*34
#define NPX   36992.0      // 32*34*34
#define CHW   73984        // 64*34*34
#define HW2   1156         // 34*34

// ---------------- init: zero accumulators ----------------
__global__ void initStatsK(double* statd, int* counts) {
    int i = threadIdx.x + blockIdx.x * blockDim.x;
    if (i < 1537) statd[i] = 0.0;
    if (i < 512) counts[i] = 0;
}

// ---------------- codebook squared norms (float + double) ----------------
__global__ void csqK(const float* __restrict__ cb, float* __restrict__ csqf,
                     double* __restrict__ csqd) {
    int k = threadIdx.x + blockIdx.x * blockDim.x;
    if (k < 512) {
        const float* r = cb + (size_t)k * 64;
        float s = 0.f; double sd = 0.0;
        for (int d = 0; d < 64; ++d) {
            s = fmaf(r[d], r[d], s);
            sd += (double)r[d] * (double)r[d];
        }
        csqf[k] = s; csqd[k] = sd;
    }
}

// ---------------- border codeword: argmin_k ||c_k||^2 (z_border = bq = 0) ----
// Also adds the 4224 border pixels' count and loss contribution.
__global__ void borderK(const double* __restrict__ csqd, int* __restrict__ kborder,
                        int* __restrict__ counts, double* __restrict__ lossAcc) {
    __shared__ double sV[512];
    __shared__ int sI[512];
    const int t = threadIdx.x;   // 512 threads
    sV[t] = csqd[t]; sI[t] = t;
    __syncthreads();
    for (int st = 256; st > 0; st >>= 1) {
        if (t < st) {
            double v2 = sV[t + st]; int i2 = sI[t + st];
            if (v2 < sV[t] || (v2 == sV[t] && i2 < sI[t])) { sV[t] = v2; sI[t] = i2; }
        }
        __syncthreads();
    }
    if (t == 0) {
        int k = sI[0];
        *kborder = k;
        atomicAdd(&counts[k], 4224);            // 32 images * 132 border px
        atomicAdd(lossAcc, 4224.0 * sV[0]);     // ||c_k - 0||^2 per border px
    }
}

// ---------------- fill all symbols with the border codeword ----------------
// out[E], E = n*73984 + d*1156 + p  <-  cb[kb*64 + d]. Interior overwritten later.
__global__ __launch_bounds__(256) void fillK(const int* __restrict__ kborder,
                                             const float* __restrict__ cb,
                                             float* __restrict__ out) {
    const int kb = *kborder;
    int E = blockIdx.x * 256 + threadIdx.x;
    if (E < SYM_N) {
        int d = (E / HW2) & 63;
        out[E] = cb[(size_t)kb * 64 + d];
    }
}

// ---------------- conv 4x4 stride2 pad1 ----------------
// block: 256 thr -> tile 64co x (8 rows x 16 cols); per-thread 8co x 4rows.
template<int CIN, int COUT, int IH, int IW, bool BN_IN, bool STORE, bool STATS>
__global__ __launch_bounds__(256) void conv4x4s2K(
    const float* __restrict__ in, const float* __restrict__ wgt,
    const float* __restrict__ bias,
    const float* __restrict__ inScale, const float* __restrict__ inShift,
    float* __restrict__ out, double* __restrict__ gSum, double* __restrict__ gSq)
{
    constexpr int OH = IH / 2, OW = IW / 2;
    constexpr int COLB = OW / 16;
    __shared__ float sIn[8 * 18 * 34];
    __shared__ float sW[128 * 64];
    __shared__ float sStat[128];

    const int tid = threadIdx.x;
    const int tx = tid & 15, ty = tid >> 4;
    const int cog = ty & 7, rg = ty >> 3;
    const int n = blockIdx.z;
    const int coBase = blockIdx.y * 64;
    const int brow = blockIdx.x / COLB, bcol = blockIdx.x % COLB;
    const int oh0 = brow * 8, ow0 = bcol * 16;
    const int ihb = oh0 * 2 - 1, iwb = ow0 * 2 - 1;

    float acc[8][4];
#pragma unroll
    for (int j = 0; j < 8; ++j)
#pragma unroll
        for (int r = 0; r < 4; ++r) acc[j][r] = 0.f;

    for (int c0 = 0; c0 < CIN; c0 += 8) {
        const int CC = (CIN - c0 < 8) ? (CIN - c0) : 8;
        for (int i = tid; i < 8 * 18 * 34; i += 256) {
            int ci = i / 612; int rem = i - ci * 612;
            int ih = rem / 34; int iw = rem - ih * 34;
            float v = 0.f;
            int gh = ihb + ih, gw = iwb + iw;
            if (ci < CC && (unsigned)gh < (unsigned)IH && (unsigned)gw < (unsigned)IW) {
                float r0 = in[(((size_t)n * CIN + (c0 + ci)) * IH + gh) * IW + gw];
                if (BN_IN) r0 = fmaxf(fmaf(r0, inScale[c0 + ci], inShift[c0 + ci]), 0.f);
                v = r0;
            }
            sIn[i] = v;
        }
        for (int i = tid; i < 8192; i += 256) {
            int co = i >> 7, r = i & 127;
            int ci = r >> 4, t = r & 15;
            float v = 0.f;
            if (ci < CC) v = wgt[(((size_t)(coBase + co)) * CIN + (c0 + ci)) * 16 + t];
            sW[r * 64 + (co ^ ((r & 7) << 3))] = v;
        }
        __syncthreads();
        for (int ci = 0; ci < CC; ++ci) {
#pragma unroll
            for (int kh = 0; kh < 4; ++kh) {
#pragma unroll
                for (int kw = 0; kw < 4; ++kw) {
                    const int tap = kh * 4 + kw;
                    const float* wp = sW + (ci * 16 + tap) * 64 + ((cog * 8) ^ ((tap & 7) << 3));
                    float4 wa = *(const float4*)wp;
                    float4 wb = *(const float4*)(wp + 4);
                    const float* ip = sIn + (ci * 18 + rg * 8 + kh) * 34 + tx * 2 + kw;
                    float wv[8] = {wa.x, wa.y, wa.z, wa.w, wb.x, wb.y, wb.z, wb.w};
                    float iv[4] = {ip[0], ip[68], ip[136], ip[204]};
#pragma unroll
                    for (int j = 0; j < 8; ++j)
#pragma unroll
                        for (int r = 0; r < 4; ++r)
                            acc[j][r] = fmaf(wv[j], iv[r], acc[j][r]);
                }
            }
        }
        __syncthreads();
    }

    if (STATS) {
        if (tid < 128) sStat[tid] = 0.f;
        __syncthreads();
    }

    const int coG = coBase + cog * 8;
#pragma unroll
    for (int j = 0; j < 8; ++j) {
        float bv = bias[coG + j];
        float s = 0.f, s2 = 0.f;
#pragma unroll
        for (int r = 0; r < 4; ++r) {
            float v = acc[j][r] + bv;
            if (STORE)
                out[(((size_t)n * COUT + coG + j) * OH + (oh0 + rg * 4 + r)) * OW + ow0 + tx] = v;
            s += v; s2 = fmaf(v, v, s2);
        }
        if (STATS) {
#pragma unroll
            for (int m = 1; m < 16; m <<= 1) {
                s  += __shfl_xor(s, m, 64);
                s2 += __shfl_xor(s2, m, 64);
            }
            if (tx == 0) {
                atomicAdd(&sStat[cog * 8 + j], s);
                atomicAdd(&sStat[64 + cog * 8 + j], s2);
            }
        }
    }
    if (STATS) {
        __syncthreads();
        if (tid < 64) {
            atomicAdd(&gSum[coBase + tid], (double)sStat[tid]);
            atomicAdd(&gSq[coBase + tid],  (double)sStat[64 + tid]);
        }
    }
}

// ---------------- BN finalize ----------------
__global__ void bnFinK(const double* __restrict__ gSum, const double* __restrict__ gSq,
                       const float* __restrict__ g, const float* __restrict__ be,
                       float* __restrict__ scale, float* __restrict__ shift,
                       int C, double cnt)
{
    int c = threadIdx.x;
    if (c < C) {
        double m = gSum[c] / cnt;
        double v = gSq[c] / cnt - m * m;
        double sc = (double)g[c] / sqrt(v + 1e-5);
        scale[c] = (float)sc;
        shift[c] = (float)((double)be[c] - m * sc);
    }
}

// ---------------- 1x1 conv (interior 32x32 px) with fused BN3+ReLU ----------------
__global__ __launch_bounds__(256) void convqK(
    const float* __restrict__ y3, const float* __restrict__ wq,
    const float* __restrict__ bq,
    const float* __restrict__ sc3, const float* __restrict__ sh3,
    float* __restrict__ z)
{
    __shared__ float sWq[64 * 68];
    __shared__ float sS[64], sH[64];
    const int tid = threadIdx.x;
    const int px = blockIdx.x * 256 + tid;
    const int n = px >> 10, hw = px & 1023;

    float accv[64];
#pragma unroll
    for (int d = 0; d < 64; ++d) accv[d] = 0.f;

    const float* base = y3 + (((size_t)n * 256) << 10) + hw;
    for (int c0 = 0; c0 < 256; c0 += 64) {
        __syncthreads();
        for (int i = tid; i < 4096; i += 256) {
            int c = i & 63, d = i >> 6;
            sWq[c * 68 + d] = wq[(size_t)d * 256 + c0 + c];
        }
        if (tid < 64) { sS[tid] = sc3[c0 + tid]; sH[tid] = sh3[c0 + tid]; }
        __syncthreads();
        for (int c = 0; c < 64; ++c) {
            float h = base[(size_t)(c0 + c) << 10];
            h = fmaxf(fmaf(h, sS[c], sH[c]), 0.f);
            const float4* wrow = (const float4*)(sWq + c * 68);
#pragma unroll
            for (int q = 0; q < 16; ++q) {
                float4 w4 = wrow[q];
                accv[4*q+0] = fmaf(h, w4.x, accv[4*q+0]);
                accv[4*q+1] = fmaf(h, w4.y, accv[4*q+1]);
                accv[4*q+2] = fmaf(h, w4.z, accv[4*q+2]);
                accv[4*q+3] = fmaf(h, w4.w, accv[4*q+3]);
            }
        }
    }
    float* zo = z + (size_t)px * 64;
    const float4* bq4 = (const float4*)bq;
#pragma unroll
    for (int q = 0; q < 16; ++q) {
        float4 b4 = bq4[q];
        float4 v;
        v.x = accv[4*q+0] + b4.x; v.y = accv[4*q+1] + b4.y;
        v.z = accv[4*q+2] + b4.z; v.w = accv[4*q+3] + b4.w;
        ((float4*)zo)[q] = v;
    }
}

// ---------------- vector quantize interior px; write to 34x34 NCHW out ------
__global__ __launch_bounds__(128) void vqK(
    const float* __restrict__ z, const float* __restrict__ cb,
    const float* __restrict__ csqf, float* __restrict__ out,
    int* __restrict__ counts, double* __restrict__ lossAcc)
{
    __shared__ float sCb[128 * 64];
    __shared__ float sCsq[128];
    const int tid = threadIdx.x;
    const int px = blockIdx.x * 128 + tid;

    float zr[64];
    const float4* zp = (const float4*)(z + (size_t)px * 64);
#pragma unroll
    for (int q = 0; q < 16; ++q) {
        float4 t = zp[q];
        zr[4*q] = t.x; zr[4*q+1] = t.y; zr[4*q+2] = t.z; zr[4*q+3] = t.w;
    }

    float best = 3.4e38f; int bidx = 0;
    for (int k0 = 0; k0 < 512; k0 += 128) {
        __syncthreads();
#pragma unroll
        for (int i = 0; i < 16; ++i)
            ((float4*)sCb)[tid + 128 * i] = ((const float4*)(cb + (size_t)k0 * 64))[tid + 128 * i];
        sCsq[tid] = csqf[k0 + tid];
        __syncthreads();
        for (int kk = 0; kk < 128; ++kk) {
            const float4* crow = (const float4*)(sCb + kk * 64);
            float d0 = 0.f, d1 = 0.f, d2 = 0.f, d3 = 0.f;
#pragma unroll
            for (int q = 0; q < 16; ++q) {
                float4 c4 = crow[q];
                d0 = fmaf(zr[4*q+0], c4.x, d0);
                d1 = fmaf(zr[4*q+1], c4.y, d1);
                d2 = fmaf(zr[4*q+2], c4.z, d2);
                d3 = fmaf(zr[4*q+3], c4.w, d3);
            }
            float dot = (d0 + d1) + (d2 + d3);
            float score = sCsq[kk] - 2.0f * dot;
            if (score < best) { best = score; bidx = k0 + kk; }
        }
    }

    atomicAdd(&counts[bidx], 1);

    // interior pixel (h,w) in 32x32 -> (h+1, w+1) in 34x34
    const int n = px >> 10, hw = px & 1023;
    const int h = hw >> 5, w = hw & 31;
    const int obase = n * CHW + (h + 1) * 34 + (w + 1);
    const float4* qp = (const float4*)(cb + (size_t)bidx * 64);
    float sq = 0.f;
#pragma unroll
    for (int q = 0; q < 16; ++q) {
        float4 c4 = qp[q];
        float vv[4] = {c4.x, c4.y, c4.z, c4.w};
#pragma unroll
        for (int j = 0; j < 4; ++j) {
            int d = 4 * q + j;
            float df = vv[j] - zr[d];
            sq = fmaf(df, df, sq);
            out[obase + d * HW2] = vv[j];
        }
    }
#pragma unroll
    for (int m = 1; m < 64; m <<= 1) sq += __shfl_xor(sq, m, 64);
    if ((tid & 63) == 0) atomicAdd(lossAcc, (double)sq);
}

// ---------------- loss + perplexity ----------------
__global__ void finalizeK(const int* __restrict__ counts,
                          const double* __restrict__ lossAcc,
                          float* __restrict__ out)
{
    const int tid = threadIdx.x;  // 64 threads
    double ent = 0.0;
    for (int k = tid; k < 512; k += 64) {
        double p = (double)counts[k] / NPX;
        ent -= p * log(p + 1e-10);
    }
#pragma unroll
    for (int m = 1; m < 64; m <<= 1) ent += __shfl_xor(ent, m, 64);
    if (tid == 0) {
        double lv = 1.25 * lossAcc[0] / (double)SYM_N;
        double pv = exp(ent);
        out[SYM_N]     = (float)lv;
        out[SYM_N + 1] = (float)pv;
    }
}

// ---------------- fallback: zero + sentinel ----------------
__global__ __launch_bounds__(256) void zeroOutK(float* __restrict__ out, int n) {
    int i = blockIdx.x * 256 + threadIdx.x;
    if (i < n) out[i] = 0.0f;
}
__global__ void sentinelK(float* out, float lossv, float perpv) {
    if (threadIdx.x == 0) { out[SYM_N] = lossv; out[SYM_N + 1] = perpv; }
}

extern "C" void kernel_launch(void* const* d_in, const int* in_sizes, int n_in,
                              void* d_out, int out_size, void* d_ws, size_t ws_size,
                              hipStream_t stream)
{
    const float* x   = (const float*)d_in[0];
    const float* w1  = (const float*)d_in[1];
    const float* b1  = (const float*)d_in[2];
    const float* g1  = (const float*)d_in[3];
    const float* be1 = (const float*)d_in[4];
    const float* w2  = (const float*)d_in[5];
    const float* b2  = (const float*)d_in[6];
    const float* g2  = (const float*)d_in[7];
    const float* be2 = (const float*)d_in[8];
    const float* w3  = (const float*)d_in[9];
    const float* b3  = (const float*)d_in[10];
    const float* g3  = (const float*)d_in[11];
    const float* be3 = (const float*)d_in[12];
    const float* wq  = (const float*)d_in[13];
    const float* bq  = (const float*)d_in[14];
    const float* cb  = (const float*)d_in[15];

    float* out = (float*)d_out;
    char* ws = (char*)d_ws;

    if (ws_size < WS_NEED) {
        zeroOutK<<<(SYM_N + 2 + 255) / 256, 256, 0, stream>>>(out, SYM_N + 2);
        sentinelK<<<1, 64, 0, stream>>>(out, -4444.0f, -5555.0f);
        return;
    }

    double* statd  = (double*)(ws);
    float*  sscale = (float*)(ws + 16384);
    int*    counts = (int*)(ws + 24576);
    float*  csqf   = (float*)(ws + 28672);
    double* csqd   = (double*)(ws + 30720);
    int*    kbord  = (int*)(ws + 34816);
    double* lossAcc = statd + 1536;

    float* h1q = (float*)(ws + H1Q_OFF);
    float* y2q = (float*)(ws + Y2Q_OFF);
    float* y3  = (float*)(ws + Y3_OFF);
    float* z   = (float*)(ws + Z_OFF);

    initStatsK<<<7, 256, 0, stream>>>(statd, counts);
    csqK<<<2, 256, 0, stream>>>(cb, csqf, csqd);
    borderK<<<1, 512, 0, stream>>>(csqd, kbord, counts, lossAcc);
    fillK<<<(SYM_N + 255) / 256, 256, 0, stream>>>(kbord, cb, out);

    // ---- phase A: conv1 stats over full batch (no store) ----
    conv4x4s2K<3, 64, 256, 256, false, false, true><<<dim3(128, 1, BATCH), 256, 0, stream>>>(
        x, w1, b1, nullptr, nullptr, nullptr, statd + 0, statd + 256);
    bnFinK<<<1, 256, 0, stream>>>(statd + 0, statd + 256, g1, be1,
                                  sscale + 0, sscale + 256, 64, 524288.0);

    // ---- phase B: conv2 stats over full batch, quarter at a time ----
    for (int q = 0; q < 4; ++q) {
        const float* xq = x + (size_t)q * QB * 3 * 256 * 256;
        conv4x4s2K<3, 64, 256, 256, false, true, false><<<dim3(128, 1, QB), 256, 0, stream>>>(
            xq, w1, b1, nullptr, nullptr, h1q, nullptr, nullptr);
        conv4x4s2K<64, 128, 128, 128, true, false, true><<<dim3(32, 2, QB), 256, 0, stream>>>(
            h1q, w2, b2, sscale + 0, sscale + 256, nullptr, statd + 512, statd + 768);
    }
    bnFinK<<<1, 256, 0, stream>>>(statd + 512, statd + 768, g2, be2,
                                  sscale + 512, sscale + 768, 128, 131072.0);

    // ---- phase C: recompute conv1+conv2, conv3 stores y3 + stats3 ----
    for (int q = 0; q < 4; ++q) {
        const float* xq = x + (size_t)q * QB * 3 * 256 * 256;
        conv4x4s2K<3, 64, 256, 256, false, true, false><<<dim3(128, 1, QB), 256, 0, stream>>>(
            xq, w1, b1, nullptr, nullptr, h1q, nullptr, nullptr);
        conv4x4s2K<64, 128, 128, 128, true, true, false><<<dim3(32, 2, QB), 256, 0, stream>>>(
            h1q, w2, b2, sscale + 0, sscale + 256, y2q, nullptr, nullptr);
        conv4x4s2K<128, 256, 64, 64, true, true, true><<<dim3(8, 4, QB), 256, 0, stream>>>(
            y2q, w3, b3, sscale + 512, sscale + 768,
            y3 + (size_t)q * QB * 256 * 1024, statd + 1024, statd + 1280);
    }
    bnFinK<<<1, 256, 0, stream>>>(statd + 1024, statd + 1280, g3, be3,
                                  sscale + 1024, sscale + 1280, 256, 32768.0);

    // ---- quantizer head (interior px) ----
    convqK<<<128, 256, 0, stream>>>(y3, wq, bq, sscale + 1024, sscale + 1280, z);
    vqK<<<256, 128, 0, stream>>>(z, cb, csqf, out, counts, lossAcc);
    finalizeK<<<1, 64, 0, stream>>>(counts, lossAcc, out);
}

// Round 8
// 1801.269 us; speedup vs baseline: 1.7738x; 1.7738x over previous
//
#include <hip/hip_runtime.h>
#include <hip/hip_bf16.h>

// SymbolicEncoder: conv(3->64,s2)+BN+ReLU -> conv(64->128,s2)+BN+ReLU ->
// conv(128->256,s2)+BN+ReLU -> 1x1 conv(256->64, padding (1,1)) -> VQ.
// z is (32,64,34,34); border px (h,w in {0,33}) have z = bq = 0.
// Output (fp32 flat): symbols (32,64,34,34) @ [0:2367488], loss @ 2367488,
// perplexity @ 2367489.
//
// Tiered pipeline by ws_size:
//   tier1 (>=201.4MB): all-fp32, each conv once, fused stats  (z == R7 bitwise)
//   tier2 (>=100.7MB): y1/y2 bf16 storage, stats on fp32 pre-rounding values
//   tier3 (>= 92.5MB): R7 recompute path (proven)

#define BATCH 32
#define QB 8

#define SYM_N 2367488      // 32*64*34*34
#define NPX   36992.0      // 32*34*34
#define CHW   73984        // 64*34*34
#define HW2   1156         // 34*34

static const unsigned long long NEED1 = 201392128ull; // 64KB + y1f(128MB) + y2f(64MB)
static const unsigned long long NEED2 = 100728832ull; // 64KB + y1h(64MB) + y2h(32MB)
static const unsigned long long NEED3 = 92536832ull;  // R7 layout

__device__ __forceinline__ float ldv(const float* p) { return *p; }
__device__ __forceinline__ float ldv(const __hip_bfloat16* p) { return __bfloat162float(*p); }
__device__ __forceinline__ void stv(float* p, float v) { *p = v; }
__device__ __forceinline__ void stv(__hip_bfloat16* p, float v) { *p = __float2bfloat16(v); }

// ---------------- init ----------------
__global__ void initStatsK(double* statd, int* counts) {
    int i = threadIdx.x + blockIdx.x * blockDim.x;
    if (i < 1537) statd[i] = 0.0;
    if (i < 512) counts[i] = 0;
}

// ---------------- codebook squared norms (float + double) ----------------
__global__ void csqK(const float* __restrict__ cb, float* __restrict__ csqf,
                     double* __restrict__ csqd) {
    int k = threadIdx.x + blockIdx.x * blockDim.x;
    if (k < 512) {
        const float* r = cb + (size_t)k * 64;
        float s = 0.f; double sd = 0.0;
        for (int d = 0; d < 64; ++d) {
            s = fmaf(r[d], r[d], s);
            sd += (double)r[d] * (double)r[d];
        }
        csqf[k] = s; csqd[k] = sd;
    }
}

// ---------------- border codeword: argmin_k ||c_k||^2 ----------------
__global__ void borderK(const double* __restrict__ csqd, int* __restrict__ kborder,
                        int* __restrict__ counts, double* __restrict__ lossAcc) {
    __shared__ double sV[512];
    __shared__ int sI[512];
    const int t = threadIdx.x;   // 512 threads
    sV[t] = csqd[t]; sI[t] = t;
    __syncthreads();
    for (int st = 256; st > 0; st >>= 1) {
        if (t < st) {
            double v2 = sV[t + st]; int i2 = sI[t + st];
            if (v2 < sV[t] || (v2 == sV[t] && i2 < sI[t])) { sV[t] = v2; sI[t] = i2; }
        }
        __syncthreads();
    }
    if (t == 0) {
        int k = sI[0];
        *kborder = k;
        atomicAdd(&counts[k], 4224);            // 32 images * 132 border px
        atomicAdd(lossAcc, 4224.0 * sV[0]);
    }
}

// ---------------- fill all symbols with the border codeword ----------------
__global__ __launch_bounds__(256) void fillK(const int* __restrict__ kborder,
                                             const float* __restrict__ cb,
                                             float* __restrict__ out) {
    const int kb = *kborder;
    int E = blockIdx.x * 256 + threadIdx.x;
    if (E < SYM_N) {
        int d = (E / HW2) & 63;
        out[E] = cb[(size_t)kb * 64 + d];
    }
}

// ---------------- conv 4x4 stride2 pad1 ----------------
// block: 256 thr -> tile 64co x (8 rows x 16 cols); per-thread 8co x 4rows.
template<int CIN, int COUT, int IH, int IW, bool BN_IN, bool STORE, bool STATS,
         typename TI, typename TO>
__global__ __launch_bounds__(256) void conv4x4s2K(
    const TI* __restrict__ in, const float* __restrict__ wgt,
    const float* __restrict__ bias,
    const float* __restrict__ inScale, const float* __restrict__ inShift,
    TO* __restrict__ out, double* __restrict__ gSum, double* __restrict__ gSq)
{
    constexpr int OH = IH / 2, OW = IW / 2;
    constexpr int COLB = OW / 16;
    __shared__ float sIn[8 * 18 * 34];
    __shared__ float sW[128 * 64];
    __shared__ float sStat[128];

    const int tid = threadIdx.x;
    const int tx = tid & 15, ty = tid >> 4;
    const int cog = ty & 7, rg = ty >> 3;
    const int n = blockIdx.z;
    const int coBase = blockIdx.y * 64;
    const int brow = blockIdx.x / COLB, bcol = blockIdx.x % COLB;
    const int oh0 = brow * 8, ow0 = bcol * 16;
    const int ihb = oh0 * 2 - 1, iwb = ow0 * 2 - 1;

    float acc[8][4];
#pragma unroll
    for (int j = 0; j < 8; ++j)
#pragma unroll
        for (int r = 0; r < 4; ++r) acc[j][r] = 0.f;

    for (int c0 = 0; c0 < CIN; c0 += 8) {
        const int CC = (CIN - c0 < 8) ? (CIN - c0) : 8;
        for (int i = tid; i < 8 * 18 * 34; i += 256) {
            int ci = i / 612; int rem = i - ci * 612;
            int ih = rem / 34; int iw = rem - ih * 34;
            float v = 0.f;
            int gh = ihb + ih, gw = iwb + iw;
            if (ci < CC && (unsigned)gh < (unsigned)IH && (unsigned)gw < (unsigned)IW) {
                float r0 = ldv(&in[(((size_t)n * CIN + (c0 + ci)) * IH + gh) * IW + gw]);
                if (BN_IN) r0 = fmaxf(fmaf(r0, inScale[c0 + ci], inShift[c0 + ci]), 0.f);
                v = r0;
            }
            sIn[i] = v;
        }
        for (int i = tid; i < 8192; i += 256) {
            int co = i >> 7, r = i & 127;
            int ci = r >> 4, t = r & 15;
            float v = 0.f;
            if (ci < CC) v = wgt[(((size_t)(coBase + co)) * CIN + (c0 + ci)) * 16 + t];
            sW[r * 64 + (co ^ ((r & 7) << 3))] = v;
        }
        __syncthreads();
        for (int ci = 0; ci < CC; ++ci) {
#pragma unroll
            for (int kh = 0; kh < 4; ++kh) {
#pragma unroll
                for (int kw = 0; kw < 4; ++kw) {
                    const int tap = kh * 4 + kw;
                    const float* wp = sW + (ci * 16 + tap) * 64 + ((cog * 8) ^ ((tap & 7) << 3));
                    float4 wa = *(const float4*)wp;
                    float4 wb = *(const float4*)(wp + 4);
                    const float* ip = sIn + (ci * 18 + rg * 8 + kh) * 34 + tx * 2 + kw;
                    float wv[8] = {wa.x, wa.y, wa.z, wa.w, wb.x, wb.y, wb.z, wb.w};
                    float iv[4] = {ip[0], ip[68], ip[136], ip[204]};
#pragma unroll
                    for (int j = 0; j < 8; ++j)
#pragma unroll
                        for (int r = 0; r < 4; ++r)
                            acc[j][r] = fmaf(wv[j], iv[r], acc[j][r]);
                }
            }
        }
        __syncthreads();
    }

    if (STATS) {
        if (tid < 128) sStat[tid] = 0.f;
        __syncthreads();
    }

    const int coG = coBase + cog * 8;
#pragma unroll
    for (int j = 0; j < 8; ++j) {
        float bv = bias[coG + j];
        float s = 0.f, s2 = 0.f;
#pragma unroll
        for (int r = 0; r < 4; ++r) {
            float v = acc[j][r] + bv;
            if (STORE)
                stv(&out[(((size_t)n * COUT + coG + j) * OH + (oh0 + rg * 4 + r)) * OW + ow0 + tx], v);
            s += v; s2 = fmaf(v, v, s2);
        }
        if (STATS) {
#pragma unroll
            for (int m = 1; m < 16; m <<= 1) {
                s  += __shfl_xor(s, m, 64);
                s2 += __shfl_xor(s2, m, 64);
            }
            if (tx == 0) {
                atomicAdd(&sStat[cog * 8 + j], s);
                atomicAdd(&sStat[64 + cog * 8 + j], s2);
            }
        }
    }
    if (STATS) {
        __syncthreads();
        if (tid < 64) {
            atomicAdd(&gSum[coBase + tid], (double)sStat[tid]);
            atomicAdd(&gSq[coBase + tid],  (double)sStat[64 + tid]);
        }
    }
}

// ---------------- BN finalize ----------------
__global__ void bnFinK(const double* __restrict__ gSum, const double* __restrict__ gSq,
                       const float* __restrict__ g, const float* __restrict__ be,
                       float* __restrict__ scale, float* __restrict__ shift,
                       int C, double cnt)
{
    int c = threadIdx.x;
    if (c < C) {
        double m = gSum[c] / cnt;
        double v = gSq[c] / cnt - m * m;
        double sc = (double)g[c] / sqrt(v + 1e-5);
        scale[c] = (float)sc;
        shift[c] = (float)((double)be[c] - m * sc);
    }
}

// ---------------- 1x1 conv (interior px) with fused BN3+ReLU ----------------
// 128 thr/block, 256 blocks (was 256x128: half the CUs idle).
__global__ __launch_bounds__(128) void convqK(
    const float* __restrict__ y3, const float* __restrict__ wq,
    const float* __restrict__ bq,
    const float* __restrict__ sc3, const float* __restrict__ sh3,
    float* __restrict__ z)
{
    __shared__ float sWq[64 * 68];
    __shared__ float sS[64], sH[64];
    const int tid = threadIdx.x;
    const int px = blockIdx.x * 128 + tid;
    const int n = px >> 10, hw = px & 1023;

    float accv[64];
#pragma unroll
    for (int d = 0; d < 64; ++d) accv[d] = 0.f;

    const float* base = y3 + (((size_t)n * 256) << 10) + hw;
    for (int c0 = 0; c0 < 256; c0 += 64) {
        __syncthreads();
        for (int i = tid; i < 4096; i += 128) {
            int c = i & 63, d = i >> 6;
            sWq[c * 68 + d] = wq[(size_t)d * 256 + c0 + c];
        }
        if (tid < 64) { sS[tid] = sc3[c0 + tid]; sH[tid] = sh3[c0 + tid]; }
        __syncthreads();
        for (int c = 0; c < 64; ++c) {
            float h = base[(size_t)(c0 + c) << 10];
            h = fmaxf(fmaf(h, sS[c], sH[c]), 0.f);
            const float4* wrow = (const float4*)(sWq + c * 68);
#pragma unroll
            for (int q = 0; q < 16; ++q) {
                float4 w4 = wrow[q];
                accv[4*q+0] = fmaf(h, w4.x, accv[4*q+0]);
                accv[4*q+1] = fmaf(h, w4.y, accv[4*q+1]);
                accv[4*q+2] = fmaf(h, w4.z, accv[4*q+2]);
                accv[4*q+3] = fmaf(h, w4.w, accv[4*q+3]);
            }
        }
    }
    float* zo = z + (size_t)px * 64;
    const float4* bq4 = (const float4*)bq;
#pragma unroll
    for (int q = 0; q < 16; ++q) {
        float4 b4 = bq4[q];
        float4 v;
        v.x = accv[4*q+0] + b4.x; v.y = accv[4*q+1] + b4.y;
        v.z = accv[4*q+2] + b4.z; v.w = accv[4*q+3] + b4.w;
        ((float4*)zo)[q] = v;
    }
}

// ---------------- vector quantize: 64 px x 4 codebook-quarters per block ------
// Same fmaf chain + lexicographic (score,idx) reduce == old sequential scan.
__global__ __launch_bounds__(256) void vqK(
    const float* __restrict__ z, const float* __restrict__ cb,
    const float* __restrict__ csqf, float* __restrict__ out,
    int* __restrict__ counts, double* __restrict__ lossAcc)
{
    const int tid = threadIdx.x;
    const int lane = tid & 63;           // px within tile (also wave lane)
    const int grp = tid >> 6;            // codebook quarter (one wave each)
    const int px = blockIdx.x * 64 + lane;

    float zr[64];
    const float4* zp = (const float4*)(z + (size_t)px * 64);
#pragma unroll
    for (int q = 0; q < 16; ++q) {
        float4 t = zp[q];
        zr[4*q] = t.x; zr[4*q+1] = t.y; zr[4*q+2] = t.z; zr[4*q+3] = t.w;
    }

    const int kbase = grp * 128;
    float best = 3.4e38f; int bidx = kbase;
    for (int kk = 0; kk < 128; ++kk) {
        const float4* crow = (const float4*)(cb + (size_t)(kbase + kk) * 64);
        float d0 = 0.f, d1 = 0.f, d2 = 0.f, d3 = 0.f;
#pragma unroll
        for (int q = 0; q < 16; ++q) {
            float4 c4 = crow[q];
            d0 = fmaf(zr[4*q+0], c4.x, d0);
            d1 = fmaf(zr[4*q+1], c4.y, d1);
            d2 = fmaf(zr[4*q+2], c4.z, d2);
            d3 = fmaf(zr[4*q+3], c4.w, d3);
        }
        float dot = (d0 + d1) + (d2 + d3);
        float score = csqf[kbase + kk] - 2.0f * dot;
        if (score < best) { best = score; bidx = kbase + kk; }
    }

    __shared__ float sB[256];
    __shared__ int   sI[256];
    sB[tid] = best; sI[tid] = bidx;
    __syncthreads();
    if (grp == 0) {
#pragma unroll
        for (int g = 1; g < 4; ++g) {
            float b = sB[lane + 64 * g]; int i = sI[lane + 64 * g];
            if (b < best || (b == best && i < bidx)) { best = b; bidx = i; }
        }
        atomicAdd(&counts[bidx], 1);

        const int n = px >> 10, hw = px & 1023;
        const int h = hw >> 5, w = hw & 31;
        const int obase = n * CHW + (h + 1) * 34 + (w + 1);
        const float4* qp = (const float4*)(cb + (size_t)bidx * 64);
        float sq = 0.f;
#pragma unroll
        for (int q = 0; q < 16; ++q) {
            float4 c4 = qp[q];
            float vv[4] = {c4.x, c4.y, c4.z, c4.w};
#pragma unroll
            for (int j = 0; j < 4; ++j) {
                int d = 4 * q + j;
                float df = vv[j] - zr[d];
                sq = fmaf(df, df, sq);
                out[obase + d * HW2] = vv[j];
            }
        }
#pragma unroll
        for (int m = 1; m < 64; m <<= 1) sq += __shfl_xor(sq, m, 64);
        if (lane == 0) atomicAdd(lossAcc, (double)sq);
    }
}

// ---------------- loss + perplexity ----------------
__global__ void finalizeK(const int* __restrict__ counts,
                          const double* __restrict__ lossAcc,
                          float* __restrict__ out)
{
    const int tid = threadIdx.x;  // 64 threads
    double ent = 0.0;
    for (int k = tid; k < 512; k += 64) {
        double p = (double)counts[k] / NPX;
        ent -= p * log(p + 1e-10);
    }
#pragma unroll
    for (int m = 1; m < 64; m <<= 1) ent += __shfl_xor(ent, m, 64);
    if (tid == 0) {
        out[SYM_N]     = (float)(1.25 * lossAcc[0] / (double)SYM_N);
        out[SYM_N + 1] = (float)exp(ent);
    }
}

// ---------------- fallback: zero + sentinel ----------------
__global__ __launch_bounds__(256) void zeroOutK(float* __restrict__ out, int n) {
    int i = blockIdx.x * 256 + threadIdx.x;
    if (i < n) out[i] = 0.0f;
}
__global__ void sentinelK(float* out, float lossv, float perpv) {
    if (threadIdx.x == 0) { out[SYM_N] = lossv; out[SYM_N + 1] = perpv; }
}

// =======================================================================
// tier 1/2: single-pass pipeline; TS = storage type of y1/y2
// =======================================================================
template<typename TS>
static void run_fast(void* const* d_in, float* out, char* ws, hipStream_t stream)
{
    const float* x   = (const float*)d_in[0];
    const float* w1  = (const float*)d_in[1];
    const float* b1  = (const float*)d_in[2];
    const float* g1  = (const float*)d_in[3];
    const float* be1 = (const float*)d_in[4];
    const float* w2  = (const float*)d_in[5];
    const float* b2  = (const float*)d_in[6];
    const float* g2  = (const float*)d_in[7];
    const float* be2 = (const float*)d_in[8];
    const float* w3  = (const float*)d_in[9];
    const float* b3  = (const float*)d_in[10];
    const float* g3  = (const float*)d_in[11];
    const float* be3 = (const float*)d_in[12];
    const float* wq  = (const float*)d_in[13];
    const float* bq  = (const float*)d_in[14];
    const float* cb  = (const float*)d_in[15];

    double* statd  = (double*)(ws);
    float*  sscale = (float*)(ws + 16384);
    int*    counts = (int*)(ws + 24576);
    float*  csqf   = (float*)(ws + 28672);
    double* csqd   = (double*)(ws + 30720);
    int*    kbord  = (int*)(ws + 34816);
    double* lossAcc = statd + 1536;

    TS* y1 = (TS*)(ws + 65536);
    TS* y2 = (TS*)(ws + 65536 + 33554432ull * sizeof(TS));
    float* y3 = (float*)(ws + 65536);                        // reuses y1 region
    float* z  = (float*)(ws + 65536 + 33554432ull);          // after y3, still in y1 region

    initStatsK<<<7, 256, 0, stream>>>(statd, counts);
    csqK<<<2, 256, 0, stream>>>(cb, csqf, csqd);
    borderK<<<1, 512, 0, stream>>>(csqd, kbord, counts, lossAcc);
    fillK<<<(SYM_N + 255) / 256, 256, 0, stream>>>(kbord, cb, out);

    conv4x4s2K<3, 64, 256, 256, false, true, true, float, TS>
        <<<dim3(128, 1, BATCH), 256, 0, stream>>>(
        x, w1, b1, nullptr, nullptr, y1, statd + 0, statd + 256);
    bnFinK<<<1, 256, 0, stream>>>(statd + 0, statd + 256, g1, be1,
                                  sscale + 0, sscale + 256, 64, 524288.0);

    conv4x4s2K<64, 128, 128, 128, true, true, true, TS, TS>
        <<<dim3(32, 2, BATCH), 256, 0, stream>>>(
        y1, w2, b2, sscale + 0, sscale + 256, y2, statd + 512, statd + 768);
    bnFinK<<<1, 256, 0, stream>>>(statd + 512, statd + 768, g2, be2,
                                  sscale + 512, sscale + 768, 128, 131072.0);

    conv4x4s2K<128, 256, 64, 64, true, true, true, TS, float>
        <<<dim3(8, 4, BATCH), 256, 0, stream>>>(
        y2, w3, b3, sscale + 512, sscale + 768, y3, statd + 1024, statd + 1280);
    bnFinK<<<1, 256, 0, stream>>>(statd + 1024, statd + 1280, g3, be3,
                                  sscale + 1024, sscale + 1280, 256, 32768.0);

    convqK<<<256, 128, 0, stream>>>(y3, wq, bq, sscale + 1024, sscale + 1280, z);
    vqK<<<512, 256, 0, stream>>>(z, cb, csqf, out, counts, lossAcc);
    finalizeK<<<1, 64, 0, stream>>>(counts, lossAcc, out);
}

// =======================================================================
// tier 3: R7 recompute path (proven)
// =======================================================================
static void run_safe(void* const* d_in, float* out, char* ws, hipStream_t stream)
{
    const float* x   = (const float*)d_in[0];
    const float* w1  = (const float*)d_in[1];
    const float* b1  = (const float*)d_in[2];
    const float* g1  = (const float*)d_in[3];
    const float* be1 = (const float*)d_in[4];
    const float* w2  = (const float*)d_in[5];
    const float* b2  = (const float*)d_in[6];
    const float* g2  = (const float*)d_in[7];
    const float* be2 = (const float*)d_in[8];
    const float* w3  = (const float*)d_in[9];
    const float* b3  = (const float*)d_in[10];
    const float* g3  = (const float*)d_in[11];
    const float* be3 = (const float*)d_in[12];
    const float* wq  = (const float*)d_in[13];
    const float* bq  = (const float*)d_in[14];
    const float* cb  = (const float*)d_in[15];

    double* statd  = (double*)(ws);
    float*  sscale = (float*)(ws + 16384);
    int*    counts = (int*)(ws + 24576);
    float*  csqf   = (float*)(ws + 28672);
    double* csqd   = (double*)(ws + 30720);
    int*    kbord  = (int*)(ws + 34816);
    double* lossAcc = statd + 1536;

    float* h1q = (float*)(ws + 262144ull);
    float* y2q = (float*)(ws + 33816576ull);
    float* y3  = (float*)(ws + 50593792ull);
    float* z   = (float*)(ws + 84148224ull);

    initStatsK<<<7, 256, 0, stream>>>(statd, counts);
    csqK<<<2, 256, 0, stream>>>(cb, csqf, csqd);
    borderK<<<1, 512, 0, stream>>>(csqd, kbord, counts, lossAcc);
    fillK<<<(SYM_N + 255) / 256, 256, 0, stream>>>(kbord, cb, out);

    conv4x4s2K<3, 64, 256, 256, false, false, true, float, float>
        <<<dim3(128, 1, BATCH), 256, 0, stream>>>(
        x, w1, b1, nullptr, nullptr, nullptr, statd + 0, statd + 256);
    bnFinK<<<1, 256, 0, stream>>>(statd + 0, statd + 256, g1, be1,
                                  sscale + 0, sscale + 256, 64, 524288.0);

    for (int q = 0; q < 4; ++q) {
        const float* xq = x + (size_t)q * QB * 3 * 256 * 256;
        conv4x4s2K<3, 64, 256, 256, false, true, false, float, float>
            <<<dim3(128, 1, QB), 256, 0, stream>>>(
            xq, w1, b1, nullptr, nullptr, h1q, nullptr, nullptr);
        conv4x4s2K<64, 128, 128, 128, true, false, true, float, float>
            <<<dim3(32, 2, QB), 256, 0, stream>>>(
            h1q, w2, b2, sscale + 0, sscale + 256, nullptr, statd + 512, statd + 768);
    }
    bnFinK<<<1, 256, 0, stream>>>(statd + 512, statd + 768, g2, be2,
                                  sscale + 512, sscale + 768, 128, 131072.0);

    for (int q = 0; q < 4; ++q) {
        const float* xq = x + (size_t)q * QB * 3 * 256 * 256;
        conv4x4s2K<3, 64, 256, 256, false, true, false, float, float>
            <<<dim3(128, 1, QB), 256, 0, stream>>>(
            xq, w1, b1, nullptr, nullptr, h1q, nullptr, nullptr);
        conv4x4s2K<64, 128, 128, 128, true, true, false, float, float>
            <<<dim3(32, 2, QB), 256, 0, stream>>>(
            h1q, w2, b2, sscale + 0, sscale + 256, y2q, nullptr, nullptr);
        conv4x4s2K<128, 256, 64, 64, true, true, true, float, float>
            <<<dim3(8, 4, QB), 256, 0, stream>>>(
            y2q, w3, b3, sscale + 512, sscale + 768,
            y3 + (size_t)q * QB * 256 * 1024, statd + 1024, statd + 1280);
    }
    bnFinK<<<1, 256, 0, stream>>>(statd + 1024, statd + 1280, g3, be3,
                                  sscale + 1024, sscale + 1280, 256, 32768.0);

    convqK<<<256, 128, 0, stream>>>(y3, wq, bq, sscale + 1024, sscale + 1280, z);
    vqK<<<512, 256, 0, stream>>>(z, cb, csqf, out, counts, lossAcc);
    finalizeK<<<1, 64, 0, stream>>>(counts, lossAcc, out);
}

extern "C" void kernel_launch(void* const* d_in, const int* in_sizes, int n_in,
                              void* d_out, int out_size, void* d_ws, size_t ws_size,
                              hipStream_t stream)
{
    float* out = (float*)d_out;
    char* ws = (char*)d_ws;

    if (ws_size >= NEED1) {
        run_fast<float>(d_in, out, ws, stream);
    } else if (ws_size >= NEED2) {
        run_fast<__hip_bfloat16>(d_in, out, ws, stream);
    } else if (ws_size >= NEED3) {
        run_safe(d_in, out, ws, stream);
    } else {
        zeroOutK<<<(SYM_N + 2 + 255) / 256, 256, 0, stream>>>(out, SYM_N + 2);
        sentinelK<<<1, 64, 0, stream>>>(out, -4444.0f, -5555.0f);
    }
}

// Round 9
// 1631.972 us; speedup vs baseline: 1.9578x; 1.1037x over previous
//
#include <hip/hip_runtime.h>
#include <hip/hip_bf16.h>

// SymbolicEncoder: conv(3->64,s2)+BN+ReLU -> conv(64->128,s2)+BN+ReLU ->
// conv(128->256,s2)+BN+ReLU -> 1x1 conv(256->64, padding (1,1)) -> VQ.
// z is (32,64,34,34); border px (h,w in {0,33}) have z = bq = 0.
// Output (fp32 flat): symbols (32,64,34,34) @ [0:2367488], loss @ 2367488,
// perplexity @ 2367489.

#define BATCH 32
#define QB 8

#define SYM_N 2367488      // 32*64*34*34
#define NPX   36992.0      // 32*34*34
#define CHW   73984        // 64*34*34
#define HW2   1156         // 34*34

static const unsigned long long NEED1 = 201392128ull;
static const unsigned long long NEED2 = 100728832ull;
static const unsigned long long NEED3 = 92536832ull;

__device__ __forceinline__ float ldv(const float* p) { return *p; }
__device__ __forceinline__ float ldv(const __hip_bfloat16* p) { return __bfloat162float(*p); }
__device__ __forceinline__ void stv(float* p, float v) { *p = v; }
__device__ __forceinline__ void stv(__hip_bfloat16* p, float v) { *p = __float2bfloat16(v); }

// ---------------- init ----------------
__global__ void initStatsK(double* statd, int* counts) {
    int i = threadIdx.x + blockIdx.x * blockDim.x;
    if (i < 1537) statd[i] = 0.0;
    if (i < 512) counts[i] = 0;
}

// ---------------- codebook squared norms (float + double) ----------------
__global__ void csqK(const float* __restrict__ cb, float* __restrict__ csqf,
                     double* __restrict__ csqd) {
    int k = threadIdx.x + blockIdx.x * blockDim.x;
    if (k < 512) {
        const float* r = cb + (size_t)k * 64;
        float s = 0.f; double sd = 0.0;
        for (int d = 0; d < 64; ++d) {
            s = fmaf(r[d], r[d], s);
            sd += (double)r[d] * (double)r[d];
        }
        csqf[k] = s; csqd[k] = sd;
    }
}

// ---------------- border codeword: argmin_k ||c_k||^2 ----------------
__global__ void borderK(const double* __restrict__ csqd, int* __restrict__ kborder,
                        int* __restrict__ counts, double* __restrict__ lossAcc) {
    __shared__ double sV[512];
    __shared__ int sI[512];
    const int t = threadIdx.x;   // 512 threads
    sV[t] = csqd[t]; sI[t] = t;
    __syncthreads();
    for (int st = 256; st > 0; st >>= 1) {
        if (t < st) {
            double v2 = sV[t + st]; int i2 = sI[t + st];
            if (v2 < sV[t] || (v2 == sV[t] && i2 < sI[t])) { sV[t] = v2; sI[t] = i2; }
        }
        __syncthreads();
    }
    if (t == 0) {
        int k = sI[0];
        *kborder = k;
        atomicAdd(&counts[k], 4224);
        atomicAdd(lossAcc, 4224.0 * sV[0]);
    }
}

// ---------------- fill all symbols with the border codeword ----------------
__global__ __launch_bounds__(256) void fillK(const int* __restrict__ kborder,
                                             const float* __restrict__ cb,
                                             float* __restrict__ out) {
    const int kb = *kborder;
    int E = blockIdx.x * 256 + threadIdx.x;
    if (E < SYM_N) {
        int d = (E / HW2) & 63;
        out[E] = cb[(size_t)kb * 64 + d];
    }
}

// ---------------- conv 4x4 stride2 pad1 (legacy tile; used for conv1) --------
template<int CIN, int COUT, int IH, int IW, bool BN_IN, bool STORE, bool STATS,
         typename TI, typename TO>
__global__ __launch_bounds__(256) void conv4x4s2K(
    const TI* __restrict__ in, const float* __restrict__ wgt,
    const float* __restrict__ bias,
    const float* __restrict__ inScale, const float* __restrict__ inShift,
    TO* __restrict__ out, double* __restrict__ gSum, double* __restrict__ gSq)
{
    constexpr int OH = IH / 2, OW = IW / 2;
    constexpr int COLB = OW / 16;
    __shared__ float sIn[8 * 18 * 34];
    __shared__ float sW[128 * 64];
    __shared__ float sStat[128];

    const int tid = threadIdx.x;
    const int tx = tid & 15, ty = tid >> 4;
    const int cog = ty & 7, rg = ty >> 3;
    const int n = blockIdx.z;
    const int coBase = blockIdx.y * 64;
    const int brow = blockIdx.x / COLB, bcol = blockIdx.x % COLB;
    const int oh0 = brow * 8, ow0 = bcol * 16;
    const int ihb = oh0 * 2 - 1, iwb = ow0 * 2 - 1;

    float acc[8][4];
#pragma unroll
    for (int j = 0; j < 8; ++j)
#pragma unroll
        for (int r = 0; r < 4; ++r) acc[j][r] = 0.f;

    for (int c0 = 0; c0 < CIN; c0 += 8) {
        const int CC = (CIN - c0 < 8) ? (CIN - c0) : 8;
        for (int i = tid; i < 8 * 18 * 34; i += 256) {
            int ci = i / 612; int rem = i - ci * 612;
            int ih = rem / 34; int iw = rem - ih * 34;
            float v = 0.f;
            int gh = ihb + ih, gw = iwb + iw;
            if (ci < CC && (unsigned)gh < (unsigned)IH && (unsigned)gw < (unsigned)IW) {
                float r0 = ldv(&in[(((size_t)n * CIN + (c0 + ci)) * IH + gh) * IW + gw]);
                if (BN_IN) r0 = fmaxf(fmaf(r0, inScale[c0 + ci], inShift[c0 + ci]), 0.f);
                v = r0;
            }
            sIn[i] = v;
        }
        for (int i = tid; i < 8192; i += 256) {
            int co = i >> 7, r = i & 127;
            int ci = r >> 4, t = r & 15;
            float v = 0.f;
            if (ci < CC) v = wgt[(((size_t)(coBase + co)) * CIN + (c0 + ci)) * 16 + t];
            sW[r * 64 + (co ^ ((r & 7) << 3))] = v;
        }
        __syncthreads();
        for (int ci = 0; ci < CC; ++ci) {
#pragma unroll
            for (int kh = 0; kh < 4; ++kh) {
#pragma unroll
                for (int kw = 0; kw < 4; ++kw) {
                    const int tap = kh * 4 + kw;
                    const float* wp = sW + (ci * 16 + tap) * 64 + ((cog * 8) ^ ((tap & 7) << 3));
                    float4 wa = *(const float4*)wp;
                    float4 wb = *(const float4*)(wp + 4);
                    const float* ip = sIn + (ci * 18 + rg * 8 + kh) * 34 + tx * 2 + kw;
                    float wv[8] = {wa.x, wa.y, wa.z, wa.w, wb.x, wb.y, wb.z, wb.w};
                    float iv[4] = {ip[0], ip[68], ip[136], ip[204]};
#pragma unroll
                    for (int j = 0; j < 8; ++j)
#pragma unroll
                        for (int r = 0; r < 4; ++r)
                            acc[j][r] = fmaf(wv[j], iv[r], acc[j][r]);
                }
            }
        }
        __syncthreads();
    }

    if (STATS) {
        if (tid < 128) sStat[tid] = 0.f;
        __syncthreads();
    }

    const int coG = coBase + cog * 8;
#pragma unroll
    for (int j = 0; j < 8; ++j) {
        float bv = bias[coG + j];
        float s = 0.f, s2 = 0.f;
#pragma unroll
        for (int r = 0; r < 4; ++r) {
            float v = acc[j][r] + bv;
            if (STORE)
                stv(&out[(((size_t)n * COUT + coG + j) * OH + (oh0 + rg * 4 + r)) * OW + ow0 + tx], v);
            s += v; s2 = fmaf(v, v, s2);
        }
        if (STATS) {
#pragma unroll
            for (int m = 1; m < 16; m <<= 1) {
                s  += __shfl_xor(s, m, 64);
                s2 += __shfl_xor(s2, m, 64);
            }
            if (tx == 0) {
                atomicAdd(&sStat[cog * 8 + j], s);
                atomicAdd(&sStat[64 + cog * 8 + j], s2);
            }
        }
    }
    if (STATS) {
        __syncthreads();
        if (tid < 64) {
            atomicAdd(&gSum[coBase + tid], (double)sStat[tid]);
            atomicAdd(&gSq[coBase + tid],  (double)sStat[64 + tid]);
        }
    }
}

// ---------------- conv 4x4 stride2 pad1 -- 8co x 8px tile (conv2/conv3) ------
// block: 256 thr = 8 co-groups x 32 px-slots; per-thread 8co x (4oh x 2ow).
// Tile: 64co x TH x TW px; 4-ci LDS chunks. Per-output FMA order == legacy.
template<int CIN, int COUT, int IH, int IW, int TH, int TW, bool BN_IN,
         bool STORE, bool STATS, typename TI, typename TO>
__global__ __launch_bounds__(256, 3) void conv8K(
    const TI* __restrict__ in, const float* __restrict__ wgt,
    const float* __restrict__ bias,
    const float* __restrict__ inScale, const float* __restrict__ inShift,
    TO* __restrict__ out, double* __restrict__ gSum, double* __restrict__ gSq)
{
    constexpr int OH = IH / 2, OW = IW / 2;
    constexpr int COLB = OW / TW;
    constexpr int SW = TW / 2;                 // px-slots along w
    constexpr int ITH = TH * 2 + 2;
    constexpr int ITWP = TW * 2 + 4;           // padded to 16B multiple
    constexpr int INSZ = 4 * ITH * ITWP;

    __shared__ float sIn[INSZ];
    __shared__ float sW[4 * 16 * 64];          // [ci*16+tap][co]
    __shared__ float sStat[128];

    const int tid = threadIdx.x;
    const int s = tid & 31, cog = tid >> 5;
    const int sw = s & (SW - 1), sh = s / SW;
    const int n = blockIdx.z;
    const int coBase = blockIdx.y * 64;
    const int brow = blockIdx.x / COLB, bcol = blockIdx.x % COLB;
    const int oh0 = brow * TH, ow0 = bcol * TW;
    const int ihb = oh0 * 2 - 1, iwb = ow0 * 2 - 1;

    float acc[8][8];   // [co][r*2+j]
#pragma unroll
    for (int c = 0; c < 8; ++c)
#pragma unroll
        for (int p = 0; p < 8; ++p) acc[c][p] = 0.f;

    for (int c0 = 0; c0 < CIN; c0 += 4) {
        const int CC = (CIN - c0 < 4) ? (CIN - c0) : 4;
        // ---- stage input 4ci x ITH x ITWP (zero-fill pad) ----
        for (int i = tid; i < INSZ; i += 256) {
            int ci = i / (ITH * ITWP); int rem = i - ci * (ITH * ITWP);
            int ih = rem / ITWP; int iw = rem - ih * ITWP;
            float v = 0.f;
            int gh = ihb + ih, gw = iwb + iw;
            if (ci < CC && (unsigned)gh < (unsigned)IH && (unsigned)gw < (unsigned)IW) {
                float r0 = ldv(&in[(((size_t)n * CIN + (c0 + ci)) * IH + gh) * IW + gw]);
                if (BN_IN) r0 = fmaxf(fmaf(r0, inScale[c0 + ci], inShift[c0 + ci]), 0.f);
                v = r0;
            }
            sIn[i] = v;
        }
        // ---- stage weights co-major (conflict-free writes) ----
        for (int i = tid; i < 4096; i += 256) {
            int r = i >> 6, co = i & 63;
            int ci = r >> 4, tap = r & 15;
            float v = (ci < CC) ? wgt[(((size_t)(coBase + co)) * CIN + (c0 + ci)) * 16 + tap] : 0.f;
            sW[r * 64 + co] = v;
        }
        __syncthreads();
        for (int ci = 0; ci < CC; ++ci) {
#pragma unroll
            for (int kh = 0; kh < 4; ++kh) {
                float inv[4][8];
#pragma unroll
                for (int r = 0; r < 4; ++r) {
                    const float* ip = sIn + (ci * ITH + (sh * 4 + r) * 2 + kh) * ITWP + sw * 4;
                    float4 a = *(const float4*)ip;
                    float4 b = *(const float4*)(ip + 4);
                    inv[r][0] = a.x; inv[r][1] = a.y; inv[r][2] = a.z; inv[r][3] = a.w;
                    inv[r][4] = b.x; inv[r][5] = b.y; inv[r][6] = b.z; inv[r][7] = b.w;
                }
#pragma unroll
                for (int kw = 0; kw < 4; ++kw) {
                    const float* wp = sW + (ci * 16 + kh * 4 + kw) * 64 + cog * 8;
                    float4 wa = *(const float4*)wp;
                    float4 wb = *(const float4*)(wp + 4);
                    float wv[8] = {wa.x, wa.y, wa.z, wa.w, wb.x, wb.y, wb.z, wb.w};
#pragma unroll
                    for (int c = 0; c < 8; ++c)
#pragma unroll
                        for (int r = 0; r < 4; ++r)
#pragma unroll
                            for (int j = 0; j < 2; ++j)
                                acc[c][r * 2 + j] =
                                    fmaf(wv[c], inv[r][2 * j + kw], acc[c][r * 2 + j]);
                }
            }
        }
        __syncthreads();
    }

    if (STATS) {
        if (tid < 128) sStat[tid] = 0.f;
        __syncthreads();
    }

    const int coG = coBase + cog * 8;
#pragma unroll
    for (int c = 0; c < 8; ++c) {
        float bv = bias[coG + c];
        float s1 = 0.f, s2 = 0.f;
#pragma unroll
        for (int p = 0; p < 8; ++p) {
            float v = acc[c][p] + bv;
            int oh = oh0 + sh * 4 + (p >> 1), ow = ow0 + sw * 2 + (p & 1);
            if (STORE)
                stv(&out[(((size_t)n * COUT + coG + c) * OH + oh) * OW + ow], v);
            s1 += v; s2 = fmaf(v, v, s2);
        }
        if (STATS) {
#pragma unroll
            for (int m = 1; m < 32; m <<= 1) {
                s1 += __shfl_xor(s1, m, 64);
                s2 += __shfl_xor(s2, m, 64);
            }
            if ((tid & 31) == 0) {
                atomicAdd(&sStat[cog * 8 + c], s1);
                atomicAdd(&sStat[64 + cog * 8 + c], s2);
            }
        }
    }
    if (STATS) {
        __syncthreads();
        if (tid < 64) {
            atomicAdd(&gSum[coBase + tid], (double)sStat[tid]);
            atomicAdd(&gSq[coBase + tid],  (double)sStat[64 + tid]);
        }
    }
}

// ---------------- BN finalize ----------------
__global__ void bnFinK(const double* __restrict__ gSum, const double* __restrict__ gSq,
                       const float* __restrict__ g, const float* __restrict__ be,
                       float* __restrict__ scale, float* __restrict__ shift,
                       int C, double cnt)
{
    int c = threadIdx.x;
    if (c < C) {
        double m = gSum[c] / cnt;
        double v = gSq[c] / cnt - m * m;
        double sc = (double)g[c] / sqrt(v + 1e-5);
        scale[c] = (float)sc;
        shift[c] = (float)((double)be[c] - m * sc);
    }
}

// ---------------- 1x1 conv (interior px) with fused BN3+ReLU ----------------
__global__ __launch_bounds__(128) void convqK(
    const float* __restrict__ y3, const float* __restrict__ wq,
    const float* __restrict__ bq,
    const float* __restrict__ sc3, const float* __restrict__ sh3,
    float* __restrict__ z)
{
    __shared__ float sWq[64 * 68];
    __shared__ float sS[64], sH[64];
    const int tid = threadIdx.x;
    const int px = blockIdx.x * 128 + tid;
    const int n = px >> 10, hw = px & 1023;

    float accv[64];
#pragma unroll
    for (int d = 0; d < 64; ++d) accv[d] = 0.f;

    const float* base = y3 + (((size_t)n * 256) << 10) + hw;
    for (int c0 = 0; c0 < 256; c0 += 64) {
        __syncthreads();
        for (int i = tid; i < 4096; i += 128) {
            int c = i & 63, d = i >> 6;
            sWq[c * 68 + d] = wq[(size_t)d * 256 + c0 + c];
        }
        if (tid < 64) { sS[tid] = sc3[c0 + tid]; sH[tid] = sh3[c0 + tid]; }
        __syncthreads();
        for (int c = 0; c < 64; ++c) {
            float h = base[(size_t)(c0 + c) << 10];
            h = fmaxf(fmaf(h, sS[c], sH[c]), 0.f);
            const float4* wrow = (const float4*)(sWq + c * 68);
#pragma unroll
            for (int q = 0; q < 16; ++q) {
                float4 w4 = wrow[q];
                accv[4*q+0] = fmaf(h, w4.x, accv[4*q+0]);
                accv[4*q+1] = fmaf(h, w4.y, accv[4*q+1]);
                accv[4*q+2] = fmaf(h, w4.z, accv[4*q+2]);
                accv[4*q+3] = fmaf(h, w4.w, accv[4*q+3]);
            }
        }
    }
    float* zo = z + (size_t)px * 64;
    const float4* bq4 = (const float4*)bq;
#pragma unroll
    for (int q = 0; q < 16; ++q) {
        float4 b4 = bq4[q];
        float4 v;
        v.x = accv[4*q+0] + b4.x; v.y = accv[4*q+1] + b4.y;
        v.z = accv[4*q+2] + b4.z; v.w = accv[4*q+3] + b4.w;
        ((float4*)zo)[q] = v;
    }
}

// ---------------- vector quantize: 64 px x 4 codebook-quarters per block -----
__global__ __launch_bounds__(256) void vqK(
    const float* __restrict__ z, const float* __restrict__ cb,
    const float* __restrict__ csqf, float* __restrict__ out,
    int* __restrict__ counts, double* __restrict__ lossAcc)
{
    const int tid = threadIdx.x;
    const int lane = tid & 63;
    const int grp = tid >> 6;
    const int px = blockIdx.x * 64 + lane;

    float zr[64];
    const float4* zp = (const float4*)(z + (size_t)px * 64);
#pragma unroll
    for (int q = 0; q < 16; ++q) {
        float4 t = zp[q];
        zr[4*q] = t.x; zr[4*q+1] = t.y; zr[4*q+2] = t.z; zr[4*q+3] = t.w;
    }

    const int kbase = grp * 128;
    float best = 3.4e38f; int bidx = kbase;
    for (int kk = 0; kk < 128; ++kk) {
        const float4* crow = (const float4*)(cb + (size_t)(kbase + kk) * 64);
        float d0 = 0.f, d1 = 0.f, d2 = 0.f, d3 = 0.f;
#pragma unroll
        for (int q = 0; q < 16; ++q) {
            float4 c4 = crow[q];
            d0 = fmaf(zr[4*q+0], c4.x, d0);
            d1 = fmaf(zr[4*q+1], c4.y, d1);
            d2 = fmaf(zr[4*q+2], c4.z, d2);
            d3 = fmaf(zr[4*q+3], c4.w, d3);
        }
        float dot = (d0 + d1) + (d2 + d3);
        float score = csqf[kbase + kk] - 2.0f * dot;
        if (score < best) { best = score; bidx = kbase + kk; }
    }

    __shared__ float sB[256];
    __shared__ int   sI[256];
    sB[tid] = best; sI[tid] = bidx;
    __syncthreads();
    if (grp == 0) {
#pragma unroll
        for (int g = 1; g < 4; ++g) {
            float b = sB[lane + 64 * g]; int i = sI[lane + 64 * g];
            if (b < best || (b == best && i < bidx)) { best = b; bidx = i; }
        }
        atomicAdd(&counts[bidx], 1);

        const int n = px >> 10, hw = px & 1023;
        const int h = hw >> 5, w = hw & 31;
        const int obase = n * CHW + (h + 1) * 34 + (w + 1);
        const float4* qp = (const float4*)(cb + (size_t)bidx * 64);
        float sq = 0.f;
#pragma unroll
        for (int q = 0; q < 16; ++q) {
            float4 c4 = qp[q];
            float vv[4] = {c4.x, c4.y, c4.z, c4.w};
#pragma unroll
            for (int j = 0; j < 4; ++j) {
                int d = 4 * q + j;
                float df = vv[j] - zr[d];
                sq = fmaf(df, df, sq);
                out[obase + d * HW2] = vv[j];
            }
        }
#pragma unroll
        for (int m = 1; m < 64; m <<= 1) sq += __shfl_xor(sq, m, 64);
        if (lane == 0) atomicAdd(lossAcc, (double)sq);
    }
}

// ---------------- loss + perplexity ----------------
__global__ void finalizeK(const int* __restrict__ counts,
                          const double* __restrict__ lossAcc,
                          float* __restrict__ out)
{
    const int tid = threadIdx.x;  // 64 threads
    double ent = 0.0;
    for (int k = tid; k < 512; k += 64) {
        double p = (double)counts[k] / NPX;
        ent -= p * log(p + 1e-10);
    }
#pragma unroll
    for (int m = 1; m < 64; m <<= 1) ent += __shfl_xor(ent, m, 64);
    if (tid == 0) {
        out[SYM_N]     = (float)(1.25 * lossAcc[0] / (double)SYM_N);
        out[SYM_N + 1] = (float)exp(ent);
    }
}

// ---------------- fallback: zero + sentinel ----------------
__global__ __launch_bounds__(256) void zeroOutK(float* __restrict__ out, int n) {
    int i = blockIdx.x * 256 + threadIdx.x;
    if (i < n) out[i] = 0.0f;
}
__global__ void sentinelK(float* out, float lossv, float perpv) {
    if (threadIdx.x == 0) { out[SYM_N] = lossv; out[SYM_N + 1] = perpv; }
}

// =======================================================================
// tier 1/2: single-pass pipeline; TS = storage type of y1/y2
// =======================================================================
template<typename TS>
static void run_fast(void* const* d_in, float* out, char* ws, hipStream_t stream)
{
    const float* x   = (const float*)d_in[0];
    const float* w1  = (const float*)d_in[1];
    const float* b1  = (const float*)d_in[2];
    const float* g1  = (const float*)d_in[3];
    const float* be1 = (const float*)d_in[4];
    const float* w2  = (const float*)d_in[5];
    const float* b2  = (const float*)d_in[6];
    const float* g2  = (const float*)d_in[7];
    const float* be2 = (const float*)d_in[8];
    const float* w3  = (const float*)d_in[9];
    const float* b3  = (const float*)d_in[10];
    const float* g3  = (const float*)d_in[11];
    const float* be3 = (const float*)d_in[12];
    const float* wq  = (const float*)d_in[13];
    const float* bq  = (const float*)d_in[14];
    const float* cb  = (const float*)d_in[15];

    double* statd  = (double*)(ws);
    float*  sscale = (float*)(ws + 16384);
    int*    counts = (int*)(ws + 24576);
    float*  csqf   = (float*)(ws + 28672);
    double* csqd   = (double*)(ws + 30720);
    int*    kbord  = (int*)(ws + 34816);
    double* lossAcc = statd + 1536;

    TS* y1 = (TS*)(ws + 65536);
    TS* y2 = (TS*)(ws + 65536 + 33554432ull * sizeof(TS));
    float* y3 = (float*)(ws + 65536);
    float* z  = (float*)(ws + 65536 + 33554432ull);

    initStatsK<<<7, 256, 0, stream>>>(statd, counts);
    csqK<<<2, 256, 0, stream>>>(cb, csqf, csqd);
    borderK<<<1, 512, 0, stream>>>(csqd, kbord, counts, lossAcc);
    fillK<<<(SYM_N + 255) / 256, 256, 0, stream>>>(kbord, cb, out);

    conv4x4s2K<3, 64, 256, 256, false, true, true, float, TS>
        <<<dim3(128, 1, BATCH), 256, 0, stream>>>(
        x, w1, b1, nullptr, nullptr, y1, statd + 0, statd + 256);
    bnFinK<<<1, 256, 0, stream>>>(statd + 0, statd + 256, g1, be1,
                                  sscale + 0, sscale + 256, 64, 524288.0);

    conv8K<64, 128, 128, 128, 8, 32, true, true, true, TS, TS>
        <<<dim3(16, 2, BATCH), 256, 0, stream>>>(
        y1, w2, b2, sscale + 0, sscale + 256, y2, statd + 512, statd + 768);
    bnFinK<<<1, 256, 0, stream>>>(statd + 512, statd + 768, g2, be2,
                                  sscale + 512, sscale + 768, 128, 131072.0);

    conv8K<128, 256, 64, 64, 16, 16, true, true, true, TS, float>
        <<<dim3(4, 4, BATCH), 256, 0, stream>>>(
        y2, w3, b3, sscale + 512, sscale + 768, y3, statd + 1024, statd + 1280);
    bnFinK<<<1, 256, 0, stream>>>(statd + 1024, statd + 1280, g3, be3,
                                  sscale + 1024, sscale + 1280, 256, 32768.0);

    convqK<<<256, 128, 0, stream>>>(y3, wq, bq, sscale + 1024, sscale + 1280, z);
    vqK<<<512, 256, 0, stream>>>(z, cb, csqf, out, counts, lossAcc);
    finalizeK<<<1, 64, 0, stream>>>(counts, lossAcc, out);
}

// =======================================================================
// tier 3: recompute path (proven; only used if ws is small)
// =======================================================================
static void run_safe(void* const* d_in, float* out, char* ws, hipStream_t stream)
{
    const float* x   = (const float*)d_in[0];
    const float* w1  = (const float*)d_in[1];
    const float* b1  = (const float*)d_in[2];
    const float* g1  = (const float*)d_in[3];
    const float* be1 = (const float*)d_in[4];
    const float* w2  = (const float*)d_in[5];
    const float* b2  = (const float*)d_in[6];
    const float* g2  = (const float*)d_in[7];
    const float* be2 = (const float*)d_in[8];
    const float* w3  = (const float*)d_in[9];
    const float* b3  = (const float*)d_in[10];
    const float* g3  = (const float*)d_in[11];
    const float* be3 = (const float*)d_in[12];
    const float* wq  = (const float*)d_in[13];
    const float* bq  = (const float*)d_in[14];
    const float* cb  = (const float*)d_in[15];

    double* statd  = (double*)(ws);
    float*  sscale = (float*)(ws + 16384);
    int*    counts = (int*)(ws + 24576);
    float*  csqf   = (float*)(ws + 28672);
    double* csqd   = (double*)(ws + 30720);
    int*    kbord  = (int*)(ws + 34816);
    double* lossAcc = statd + 1536;

    float* h1q = (float*)(ws + 262144ull);
    float* y2q = (float*)(ws + 33816576ull);
    float* y3  = (float*)(ws + 50593792ull);
    float* z   = (float*)(ws + 84148224ull);

    initStatsK<<<7, 256, 0, stream>>>(statd, counts);
    csqK<<<2, 256, 0, stream>>>(cb, csqf, csqd);
    borderK<<<1, 512, 0, stream>>>(csqd, kbord, counts, lossAcc);
    fillK<<<(SYM_N + 255) / 256, 256, 0, stream>>>(kbord, cb, out);

    conv4x4s2K<3, 64, 256, 256, false, false, true, float, float>
        <<<dim3(128, 1, BATCH), 256, 0, stream>>>(
        x, w1, b1, nullptr, nullptr, nullptr, statd + 0, statd + 256);
    bnFinK<<<1, 256, 0, stream>>>(statd + 0, statd + 256, g1, be1,
                                  sscale + 0, sscale + 256, 64, 524288.0);

    for (int q = 0; q < 4; ++q) {
        const float* xq = x + (size_t)q * QB * 3 * 256 * 256;
        conv4x4s2K<3, 64, 256, 256, false, true, false, float, float>
            <<<dim3(128, 1, QB), 256, 0, stream>>>(
            xq, w1, b1, nullptr, nullptr, h1q, nullptr, nullptr);
        conv4x4s2K<64, 128, 128, 128, true, false, true, float, float>
            <<<dim3(32, 2, QB), 256, 0, stream>>>(
            h1q, w2, b2, sscale + 0, sscale + 256, nullptr, statd + 512, statd + 768);
    }
    bnFinK<<<1, 256, 0, stream>>>(statd + 512, statd + 768, g2, be2,
                                  sscale + 512, sscale + 768, 128, 131072.0);

    for (int q = 0; q < 4; ++q) {
        const float* xq = x + (size_t)q * QB * 3 * 256 * 256;
        conv4x4s2K<3, 64, 256, 256, false, true, false, float, float>
            <<<dim3(128, 1, QB), 256, 0, stream>>>(
            xq, w1, b1, nullptr, nullptr, h1q, nullptr, nullptr);
        conv4x4s2K<64, 128, 128, 128, true, true, false, float, float>
            <<<dim3(32, 2, QB), 256, 0, stream>>>(
            h1q, w2, b2, sscale + 0, sscale + 256, y2q, nullptr, nullptr);
        conv4x4s2K<128, 256, 64, 64, true, true, true, float, float>
            <<<dim3(8, 4, QB), 256, 0, stream>>>(
            y2q, w3, b3, sscale + 512, sscale + 768,
            y3 + (size_t)q * QB * 256 * 1024, statd + 1024, statd + 1280);
    }
    bnFinK<<<1, 256, 0, stream>>>(statd + 1024, statd + 1280, g3, be3,
                                  sscale + 1024, sscale + 1280, 256, 32768.0);

    convqK<<<256, 128, 0, stream>>>(y3, wq, bq, sscale + 1024, sscale + 1280, z);
    vqK<<<512, 256, 0, stream>>>(z, cb, csqf, out, counts, lossAcc);
    finalizeK<<<1, 64, 0, stream>>>(counts, lossAcc, out);
}

extern "C" void kernel_launch(void* const* d_in, const int* in_sizes, int n_in,
                              void* d_out, int out_size, void* d_ws, size_t ws_size,
                              hipStream_t stream)
{
    float* out = (float*)d_out;
    char* ws = (char*)d_ws;

    if (ws_size >= NEED1) {
        run_fast<float>(d_in, out, ws, stream);
    } else if (ws_size >= NEED2) {
        run_fast<__hip_bfloat16>(d_in, out, ws, stream);
    } else if (ws_size >= NEED3) {
        run_safe(d_in, out, ws, stream);
    } else {
        zeroOutK<<<(SYM_N + 2 + 255) / 256, 256, 0, stream>>>(out, SYM_N + 2);
        sentinelK<<<1, 64, 0, stream>>>(out, -4444.0f, -5555.0f);
    }
}

// Round 10
// 736.983 us; speedup vs baseline: 4.3353x; 2.2144x over previous
//
#include <hip/hip_runtime.h>
#include <hip/hip_bf16.h>

// SymbolicEncoder: conv(3->64,s2)+BN+ReLU -> conv(64->128,s2)+BN+ReLU ->
// conv(128->256,s2)+BN+ReLU -> 1x1 conv(256->64, padding (1,1)) -> VQ.
// z is (32,64,34,34); border px have z = bq = 0.
// Output (fp32 flat): symbols @ [0:2367488], loss @ 2367488, perp @ 2367489.
//
// R10: conv2/conv3 on matrix cores (fp16 in / fp32 acc implicit GEMM per tap).

#define BATCH 32
#define QB 8

#define SYM_N 2367488
#define NPX   36992.0
#define CHW   73984
#define HW2   1156

static const unsigned long long NEED1 = 201392128ull;
static const unsigned long long NEED2 = 100728832ull;
static const unsigned long long NEED3 = 92536832ull;

typedef _Float16 half8 __attribute__((ext_vector_type(8)));
typedef float f32x16 __attribute__((ext_vector_type(16)));

__device__ __forceinline__ float ldv(const float* p) { return *p; }
__device__ __forceinline__ float ldv(const __hip_bfloat16* p) { return __bfloat162float(*p); }
__device__ __forceinline__ void stv(float* p, float v) { *p = v; }
__device__ __forceinline__ void stv(__hip_bfloat16* p, float v) { *p = __float2bfloat16(v); }

__device__ __forceinline__ void st4(float* p, float a, float b, float c, float d) {
    float4 v; v.x = a; v.y = b; v.z = c; v.w = d;
    *(float4*)p = v;
}
__device__ __forceinline__ void st4(_Float16* p, float a, float b, float c, float d) {
    union { _Float16 h[4]; ushort4 u; } t;
    t.h[0] = (_Float16)a; t.h[1] = (_Float16)b; t.h[2] = (_Float16)c; t.h[3] = (_Float16)d;
    *(ushort4*)p = t.u;
}

// ---------------- init ----------------
__global__ void initStatsK(double* statd, int* counts) {
    int i = threadIdx.x + blockIdx.x * blockDim.x;
    if (i < 1537) statd[i] = 0.0;
    if (i < 512) counts[i] = 0;
}

// ---------------- codebook squared norms ----------------
__global__ void csqK(const float* __restrict__ cb, float* __restrict__ csqf,
                     double* __restrict__ csqd) {
    int k = threadIdx.x + blockIdx.x * blockDim.x;
    if (k < 512) {
        const float* r = cb + (size_t)k * 64;
        float s = 0.f; double sd = 0.0;
        for (int d = 0; d < 64; ++d) {
            s = fmaf(r[d], r[d], s);
            sd += (double)r[d] * (double)r[d];
        }
        csqf[k] = s; csqd[k] = sd;
    }
}

// ---------------- border codeword ----------------
__global__ void borderK(const double* __restrict__ csqd, int* __restrict__ kborder,
                        int* __restrict__ counts, double* __restrict__ lossAcc) {
    __shared__ double sV[512];
    __shared__ int sI[512];
    const int t = threadIdx.x;
    sV[t] = csqd[t]; sI[t] = t;
    __syncthreads();
    for (int st = 256; st > 0; st >>= 1) {
        if (t < st) {
            double v2 = sV[t + st]; int i2 = sI[t + st];
            if (v2 < sV[t] || (v2 == sV[t] && i2 < sI[t])) { sV[t] = v2; sI[t] = i2; }
        }
        __syncthreads();
    }
    if (t == 0) {
        int k = sI[0];
        *kborder = k;
        atomicAdd(&counts[k], 4224);
        atomicAdd(lossAcc, 4224.0 * sV[0]);
    }
}

// ---------------- fill symbols with border codeword ----------------
__global__ __launch_bounds__(256) void fillK(const int* __restrict__ kborder,
                                             const float* __restrict__ cb,
                                             float* __restrict__ out) {
    const int kb = *kborder;
    int E = blockIdx.x * 256 + threadIdx.x;
    if (E < SYM_N) {
        int d = (E / HW2) & 63;
        out[E] = cb[(size_t)kb * 64 + d];
    }
}

// ---------------- legacy conv 4x4 s2 (conv1 + fallbacks) ----------------
template<int CIN, int COUT, int IH, int IW, bool BN_IN, bool STORE, bool STATS,
         typename TI, typename TO>
__global__ __launch_bounds__(256) void conv4x4s2K(
    const TI* __restrict__ in, const float* __restrict__ wgt,
    const float* __restrict__ bias,
    const float* __restrict__ inScale, const float* __restrict__ inShift,
    TO* __restrict__ out, double* __restrict__ gSum, double* __restrict__ gSq)
{
    constexpr int OH = IH / 2, OW = IW / 2;
    constexpr int COLB = OW / 16;
    __shared__ float sIn[8 * 18 * 34];
    __shared__ float sW[128 * 64];
    __shared__ float sStat[128];

    const int tid = threadIdx.x;
    const int tx = tid & 15, ty = tid >> 4;
    const int cog = ty & 7, rg = ty >> 3;
    const int n = blockIdx.z;
    const int coBase = blockIdx.y * 64;
    const int brow = blockIdx.x / COLB, bcol = blockIdx.x % COLB;
    const int oh0 = brow * 8, ow0 = bcol * 16;
    const int ihb = oh0 * 2 - 1, iwb = ow0 * 2 - 1;

    float acc[8][4];
#pragma unroll
    for (int j = 0; j < 8; ++j)
#pragma unroll
        for (int r = 0; r < 4; ++r) acc[j][r] = 0.f;

    for (int c0 = 0; c0 < CIN; c0 += 8) {
        const int CC = (CIN - c0 < 8) ? (CIN - c0) : 8;
        for (int i = tid; i < 8 * 18 * 34; i += 256) {
            int ci = i / 612; int rem = i - ci * 612;
            int ih = rem / 34; int iw = rem - ih * 34;
            float v = 0.f;
            int gh = ihb + ih, gw = iwb + iw;
            if (ci < CC && (unsigned)gh < (unsigned)IH && (unsigned)gw < (unsigned)IW) {
                float r0 = ldv(&in[(((size_t)n * CIN + (c0 + ci)) * IH + gh) * IW + gw]);
                if (BN_IN) r0 = fmaxf(fmaf(r0, inScale[c0 + ci], inShift[c0 + ci]), 0.f);
                v = r0;
            }
            sIn[i] = v;
        }
        for (int i = tid; i < 8192; i += 256) {
            int co = i >> 7, r = i & 127;
            int ci = r >> 4, t = r & 15;
            float v = 0.f;
            if (ci < CC) v = wgt[(((size_t)(coBase + co)) * CIN + (c0 + ci)) * 16 + t];
            sW[r * 64 + (co ^ ((r & 7) << 3))] = v;
        }
        __syncthreads();
        for (int ci = 0; ci < CC; ++ci) {
#pragma unroll
            for (int kh = 0; kh < 4; ++kh) {
#pragma unroll
                for (int kw = 0; kw < 4; ++kw) {
                    const int tap = kh * 4 + kw;
                    const float* wp = sW + (ci * 16 + tap) * 64 + ((cog * 8) ^ ((tap & 7) << 3));
                    float4 wa = *(const float4*)wp;
                    float4 wb = *(const float4*)(wp + 4);
                    const float* ip = sIn + (ci * 18 + rg * 8 + kh) * 34 + tx * 2 + kw;
                    float wv[8] = {wa.x, wa.y, wa.z, wa.w, wb.x, wb.y, wb.z, wb.w};
                    float iv[4] = {ip[0], ip[68], ip[136], ip[204]};
#pragma unroll
                    for (int j = 0; j < 8; ++j)
#pragma unroll
                        for (int r = 0; r < 4; ++r)
                            acc[j][r] = fmaf(wv[j], iv[r], acc[j][r]);
                }
            }
        }
        __syncthreads();
    }

    if (STATS) {
        if (tid < 128) sStat[tid] = 0.f;
        __syncthreads();
    }

    const int coG = coBase + cog * 8;
#pragma unroll
    for (int j = 0; j < 8; ++j) {
        float bv = bias[coG + j];
        float s = 0.f, s2 = 0.f;
#pragma unroll
        for (int r = 0; r < 4; ++r) {
            float v = acc[j][r] + bv;
            if (STORE)
                stv(&out[(((size_t)n * COUT + coG + j) * OH + (oh0 + rg * 4 + r)) * OW + ow0 + tx], v);
            s += v; s2 = fmaf(v, v, s2);
        }
        if (STATS) {
#pragma unroll
            for (int m = 1; m < 16; m <<= 1) {
                s  += __shfl_xor(s, m, 64);
                s2 += __shfl_xor(s2, m, 64);
            }
            if (tx == 0) {
                atomicAdd(&sStat[cog * 8 + j], s);
                atomicAdd(&sStat[64 + cog * 8 + j], s2);
            }
        }
    }
    if (STATS) {
        __syncthreads();
        if (tid < 64) {
            atomicAdd(&gSum[coBase + tid], (double)sStat[tid]);
            atomicAdd(&gSq[coBase + tid],  (double)sStat[64 + tid]);
        }
    }
}

// ---------------- fallback conv (8co x 8px tile) ----------------
template<int CIN, int COUT, int IH, int IW, int TH, int TW, bool BN_IN,
         bool STORE, bool STATS, typename TI, typename TO>
__global__ __launch_bounds__(256, 3) void conv8K(
    const TI* __restrict__ in, const float* __restrict__ wgt,
    const float* __restrict__ bias,
    const float* __restrict__ inScale, const float* __restrict__ inShift,
    TO* __restrict__ out, double* __restrict__ gSum, double* __restrict__ gSq)
{
    constexpr int OH = IH / 2, OW = IW / 2;
    constexpr int COLB = OW / TW;
    constexpr int SW = TW / 2;
    constexpr int ITH = TH * 2 + 2;
    constexpr int ITWP = TW * 2 + 4;
    constexpr int INSZ = 4 * ITH * ITWP;

    __shared__ float sIn[INSZ];
    __shared__ float sW[4 * 16 * 64];
    __shared__ float sStat[128];

    const int tid = threadIdx.x;
    const int s = tid & 31, cog = tid >> 5;
    const int sw = s & (SW - 1), sh = s / SW;
    const int n = blockIdx.z;
    const int coBase = blockIdx.y * 64;
    const int brow = blockIdx.x / COLB, bcol = blockIdx.x % COLB;
    const int oh0 = brow * TH, ow0 = bcol * TW;
    const int ihb = oh0 * 2 - 1, iwb = ow0 * 2 - 1;

    float acc[8][8];
#pragma unroll
    for (int c = 0; c < 8; ++c)
#pragma unroll
        for (int p = 0; p < 8; ++p) acc[c][p] = 0.f;

    for (int c0 = 0; c0 < CIN; c0 += 4) {
        const int CC = (CIN - c0 < 4) ? (CIN - c0) : 4;
        for (int i = tid; i < INSZ; i += 256) {
            int ci = i / (ITH * ITWP); int rem = i - ci * (ITH * ITWP);
            int ih = rem / ITWP; int iw = rem - ih * ITWP;
            float v = 0.f;
            int gh = ihb + ih, gw = iwb + iw;
            if (ci < CC && (unsigned)gh < (unsigned)IH && (unsigned)gw < (unsigned)IW) {
                float r0 = ldv(&in[(((size_t)n * CIN + (c0 + ci)) * IH + gh) * IW + gw]);
                if (BN_IN) r0 = fmaxf(fmaf(r0, inScale[c0 + ci], inShift[c0 + ci]), 0.f);
                v = r0;
            }
            sIn[i] = v;
        }
        for (int i = tid; i < 4096; i += 256) {
            int r = i >> 6, co = i & 63;
            int ci = r >> 4, tap = r & 15;
            float v = (ci < CC) ? wgt[(((size_t)(coBase + co)) * CIN + (c0 + ci)) * 16 + tap] : 0.f;
            sW[r * 64 + co] = v;
        }
        __syncthreads();
        for (int ci = 0; ci < CC; ++ci) {
#pragma unroll
            for (int kh = 0; kh < 4; ++kh) {
                float inv[4][8];
#pragma unroll
                for (int r = 0; r < 4; ++r) {
                    const float* ip = sIn + (ci * ITH + (sh * 4 + r) * 2 + kh) * ITWP + sw * 4;
                    float4 a = *(const float4*)ip;
                    float4 b = *(const float4*)(ip + 4);
                    inv[r][0] = a.x; inv[r][1] = a.y; inv[r][2] = a.z; inv[r][3] = a.w;
                    inv[r][4] = b.x; inv[r][5] = b.y; inv[r][6] = b.z; inv[r][7] = b.w;
                }
#pragma unroll
                for (int kw = 0; kw < 4; ++kw) {
                    const float* wp = sW + (ci * 16 + kh * 4 + kw) * 64 + cog * 8;
                    float4 wa = *(const float4*)wp;
                    float4 wb = *(const float4*)(wp + 4);
                    float wv[8] = {wa.x, wa.y, wa.z, wa.w, wb.x, wb.y, wb.z, wb.w};
#pragma unroll
                    for (int c = 0; c < 8; ++c)
#pragma unroll
                        for (int r = 0; r < 4; ++r)
#pragma unroll
                            for (int j = 0; j < 2; ++j)
                                acc[c][r * 2 + j] =
                                    fmaf(wv[c], inv[r][2 * j + kw], acc[c][r * 2 + j]);
                }
            }
        }
        __syncthreads();
    }

    if (STATS) {
        if (tid < 128) sStat[tid] = 0.f;
        __syncthreads();
    }

    const int coG = coBase + cog * 8;
#pragma unroll
    for (int c = 0; c < 8; ++c) {
        float bv = bias[coG + c];
        float s1 = 0.f, s2 = 0.f;
#pragma unroll
        for (int p = 0; p < 8; ++p) {
            float v = acc[c][p] + bv;
            int oh = oh0 + sh * 4 + (p >> 1), ow = ow0 + sw * 2 + (p & 1);
            if (STORE)
                stv(&out[(((size_t)n * COUT + coG + c) * OH + oh) * OW + ow], v);
            s1 += v; s2 = fmaf(v, v, s2);
        }
        if (STATS) {
#pragma unroll
            for (int m = 1; m < 32; m <<= 1) {
                s1 += __shfl_xor(s1, m, 64);
                s2 += __shfl_xor(s2, m, 64);
            }
            if ((tid & 31) == 0) {
                atomicAdd(&sStat[cog * 8 + c], s1);
                atomicAdd(&sStat[64 + cog * 8 + c], s2);
            }
        }
    }
    if (STATS) {
        __syncthreads();
        if (tid < 64) {
            atomicAdd(&gSum[coBase + tid], (double)sStat[tid]);
            atomicAdd(&gSq[coBase + tid],  (double)sStat[64 + tid]);
        }
    }
}

// ---------------- BN finalize ----------------
__global__ void bnFinK(const double* __restrict__ gSum, const double* __restrict__ gSq,
                       const float* __restrict__ g, const float* __restrict__ be,
                       float* __restrict__ scale, float* __restrict__ shift,
                       int C, double cnt)
{
    int c = threadIdx.x;
    if (c < C) {
        double m = gSum[c] / cnt;
        double v = gSq[c] / cnt - m * m;
        double sc = (double)g[c] / sqrt(v + 1e-5);
        scale[c] = (float)sc;
        shift[c] = (float)((double)be[c] - m * sc);
    }
}

// ---------------- BN1+ReLU apply: y1 fp32 -> h1 fp16 ----------------
__global__ __launch_bounds__(256) void bnApplyK(
    const float* __restrict__ y1, const float* __restrict__ sc,
    const float* __restrict__ sh, _Float16* __restrict__ h1)
{
    size_t i = ((size_t)blockIdx.x * 256 + threadIdx.x) * 4;   // 33554432 elems total
    float4 v = *(const float4*)(y1 + i);
    int c = (int)((i >> 14) & 63);
    float s = sc[c], b = sh[c];
    union { _Float16 h[4]; ushort4 u; } o;
    o.h[0] = (_Float16)fmaxf(fmaf(v.x, s, b), 0.f);
    o.h[1] = (_Float16)fmaxf(fmaf(v.y, s, b), 0.f);
    o.h[2] = (_Float16)fmaxf(fmaf(v.z, s, b), 0.f);
    o.h[3] = (_Float16)fmaxf(fmaf(v.w, s, b), 0.f);
    *(ushort4*)(h1 + i) = o.u;
}

// ---------------- weight repack: w[co][ci][tap] fp32 -> [tap][chunk][co][16] fp16 ----
__global__ __launch_bounds__(256) void splitWK(
    const float* __restrict__ w, _Float16* __restrict__ wsOut, int CIN, int COUT)
{
    int CH = CIN >> 4;
    int total = 16 * CH * COUT * 16;
    for (int i = blockIdx.x * 256 + threadIdx.x; i < total; i += gridDim.x * 256) {
        int cil = i & 15; int r = i >> 4;
        int co = r % COUT; r /= COUT;
        int c = r % CH; int tap = r / CH;
        int ci = c * 16 + cil;
        wsOut[i] = (_Float16)w[((size_t)co * CIN + ci) * 16 + tap];
    }
}

// ---------------- MFMA conv 4x4 s2 (implicit GEMM per tap) ----------------
// block: 512 thr = 8 waves (4 M-waves x 2 N-waves). Block tile: 128 px
// (4 oh rows x 32 ow) x COUT co. Wave: 32 px x (NF*32) co via 32x32x16 f16.
// A (image) in LDS [10 ih][68 iw][16 ci, row padded to 24]; B (weights)
// read per-lane 16B direct from repacked global (L1/L2 resident).
template<int CIN, int COUT, int IH, int NF, bool BN_IN, typename TO>
__global__ __launch_bounds__(512) void convMfmaK(
    const _Float16* __restrict__ in, const _Float16* __restrict__ wsplit,
    const float* __restrict__ bias,
    const float* __restrict__ inScale, const float* __restrict__ inShift,
    TO* __restrict__ out, double* __restrict__ gSum, double* __restrict__ gSq)
{
    constexpr int OH = IH / 2;
    constexpr int OWB = OH / 32;
    constexpr int CH = CIN / 16;
    __shared__ _Float16 sA[10 * 68 * 24];
    __shared__ float sStat[2 * COUT];

    const int tid = threadIdx.x;
    const int l = tid & 63, wid = tid >> 6;
    const int lane31 = l & 31, hs = l >> 5;
    const int mw = wid & 3, nw = wid >> 2;
    const int n = blockIdx.z;
    const int ohB = (blockIdx.x / OWB) * 4;
    const int owB = (blockIdx.x % OWB) * 32;
    const int ghBase = 2 * ohB - 1, gwBase = 2 * owB - 1;

    for (int i = tid; i < 2 * COUT; i += 512) sStat[i] = 0.f;

    f32x16 acc[NF];
#pragma unroll
    for (int f = 0; f < NF; ++f)
#pragma unroll
        for (int j = 0; j < 16; ++j) acc[f][j] = 0.f;

    for (int c = 0; c < CH; ++c) {
        __syncthreads();
        for (int i = tid; i < 10 * 68 * 16; i += 512) {
            int iw = i % 68; int r = i / 68; int ih = r % 10; int cil = r / 10;
            int gh = ghBase + ih, gw = gwBase + iw;
            float v = 0.f;
            if ((unsigned)gh < (unsigned)IH && (unsigned)gw < (unsigned)IH) {
                v = (float)in[(((size_t)n * CIN + c * 16 + cil) * IH + gh) * IH + gw];
                if (BN_IN) v = fmaxf(fmaf(v, inScale[c * 16 + cil], inShift[c * 16 + cil]), 0.f);
            }
            sA[(ih * 68 + iw) * 24 + cil] = (_Float16)v;
        }
        __syncthreads();
#pragma unroll
        for (int kh = 0; kh < 4; ++kh) {
#pragma unroll
            for (int kw = 0; kw < 4; ++kw) {
                const int ihX = 2 * mw + kh;
                half8 a = *(const half8*)&sA[(ihX * 68 + 2 * lane31 + kw) * 24 + hs * 8];
                const _Float16* bp = wsplit
                    + (((size_t)(kh * 4 + kw) * CH + c) * COUT + nw * (NF * 32) + lane31) * 16
                    + hs * 8;
#pragma unroll
                for (int f = 0; f < NF; ++f) {
                    half8 b = *(const half8*)(bp + (size_t)f * 32 * 16);
                    acc[f] = __builtin_amdgcn_mfma_f32_32x32x16_f16(a, b, acc[f], 0, 0, 0);
                }
            }
        }
    }

    // epilogue: bias + store + stats
    const int oh = ohB + mw;
#pragma unroll
    for (int f = 0; f < NF; ++f) {
        int co = nw * (NF * 32) + f * 32 + lane31;
        float bv = bias[co];
        float s1 = 0.f, s2 = 0.f;
#pragma unroll
        for (int q = 0; q < 4; ++q) {
            float v0 = acc[f][q * 4 + 0] + bv;
            float v1 = acc[f][q * 4 + 1] + bv;
            float v2 = acc[f][q * 4 + 2] + bv;
            float v3 = acc[f][q * 4 + 3] + bv;
            s1 += (v0 + v1) + (v2 + v3);
            s2 = fmaf(v0, v0, s2); s2 = fmaf(v1, v1, s2);
            s2 = fmaf(v2, v2, s2); s2 = fmaf(v3, v3, s2);
            int ow = owB + q * 8 + hs * 4;
            st4(&out[(((size_t)n * COUT + co) * OH + oh) * OH + ow], v0, v1, v2, v3);
        }
        s1 += __shfl_xor(s1, 32, 64);
        s2 += __shfl_xor(s2, 32, 64);
        if (hs == 0) {
            atomicAdd(&sStat[co], s1);
            atomicAdd(&sStat[COUT + co], s2);
        }
    }
    __syncthreads();
    for (int i = tid; i < COUT; i += 512) {
        atomicAdd(&gSum[i], (double)sStat[i]);
        atomicAdd(&gSq[i],  (double)sStat[COUT + i]);
    }
}

// ---------------- 1x1 conv (interior px) with fused BN3+ReLU ----------------
__global__ __launch_bounds__(128) void convqK(
    const float* __restrict__ y3, const float* __restrict__ wq,
    const float* __restrict__ bq,
    const float* __restrict__ sc3, const float* __restrict__ sh3,
    float* __restrict__ z)
{
    __shared__ float sWq[64 * 68];
    __shared__ float sS[64], sH[64];
    const int tid = threadIdx.x;
    const int px = blockIdx.x * 128 + tid;
    const int n = px >> 10, hw = px & 1023;

    float accv[64];
#pragma unroll
    for (int d = 0; d < 64; ++d) accv[d] = 0.f;

    const float* base = y3 + (((size_t)n * 256) << 10) + hw;
    for (int c0 = 0; c0 < 256; c0 += 64) {
        __syncthreads();
        for (int i = tid; i < 4096; i += 128) {
            int c = i & 63, d = i >> 6;
            sWq[c * 68 + d] = wq[(size_t)d * 256 + c0 + c];
        }
        if (tid < 64) { sS[tid] = sc3[c0 + tid]; sH[tid] = sh3[c0 + tid]; }
        __syncthreads();
        for (int c = 0; c < 64; ++c) {
            float h = base[(size_t)(c0 + c) << 10];
            h = fmaxf(fmaf(h, sS[c], sH[c]), 0.f);
            const float4* wrow = (const float4*)(sWq + c * 68);
#pragma unroll
            for (int q = 0; q < 16; ++q) {
                float4 w4 = wrow[q];
                accv[4*q+0] = fmaf(h, w4.x, accv[4*q+0]);
                accv[4*q+1] = fmaf(h, w4.y, accv[4*q+1]);
                accv[4*q+2] = fmaf(h, w4.z, accv[4*q+2]);
                accv[4*q+3] = fmaf(h, w4.w, accv[4*q+3]);
            }
        }
    }
    float* zo = z + (size_t)px * 64;
    const float4* bq4 = (const float4*)bq;
#pragma unroll
    for (int q = 0; q < 16; ++q) {
        float4 b4 = bq4[q];
        float4 v;
        v.x = accv[4*q+0] + b4.x; v.y = accv[4*q+1] + b4.y;
        v.z = accv[4*q+2] + b4.z; v.w = accv[4*q+3] + b4.w;
        ((float4*)zo)[q] = v;
    }
}

// ---------------- vector quantize ----------------
__global__ __launch_bounds__(256) void vqK(
    const float* __restrict__ z, const float* __restrict__ cb,
    const float* __restrict__ csqf, float* __restrict__ out,
    int* __restrict__ counts, double* __restrict__ lossAcc)
{
    const int tid = threadIdx.x;
    const int lane = tid & 63;
    const int grp = tid >> 6;
    const int px = blockIdx.x * 64 + lane;

    float zr[64];
    const float4* zp = (const float4*)(z + (size_t)px * 64);
#pragma unroll
    for (int q = 0; q < 16; ++q) {
        float4 t = zp[q];
        zr[4*q] = t.x; zr[4*q+1] = t.y; zr[4*q+2] = t.z; zr[4*q+3] = t.w;
    }

    const int kbase = grp * 128;
    float best = 3.4e38f; int bidx = kbase;
    for (int kk = 0; kk < 128; ++kk) {
        const float4* crow = (const float4*)(cb + (size_t)(kbase + kk) * 64);
        float d0 = 0.f, d1 = 0.f, d2 = 0.f, d3 = 0.f;
#pragma unroll
        for (int q = 0; q < 16; ++q) {
            float4 c4 = crow[q];
            d0 = fmaf(zr[4*q+0], c4.x, d0);
            d1 = fmaf(zr[4*q+1], c4.y, d1);
            d2 = fmaf(zr[4*q+2], c4.z, d2);
            d3 = fmaf(zr[4*q+3], c4.w, d3);
        }
        float dot = (d0 + d1) + (d2 + d3);
        float score = csqf[kbase + kk] - 2.0f * dot;
        if (score < best) { best = score; bidx = kbase + kk; }
    }

    __shared__ float sB[256];
    __shared__ int   sI[256];
    sB[tid] = best; sI[tid] = bidx;
    __syncthreads();
    if (grp == 0) {
#pragma unroll
        for (int g = 1; g < 4; ++g) {
            float b = sB[lane + 64 * g]; int i = sI[lane + 64 * g];
            if (b < best || (b == best && i < bidx)) { best = b; bidx = i; }
        }
        atomicAdd(&counts[bidx], 1);

        const int n = px >> 10, hw = px & 1023;
        const int h = hw >> 5, w = hw & 31;
        const int obase = n * CHW + (h + 1) * 34 + (w + 1);
        const float4* qp = (const float4*)(cb + (size_t)bidx * 64);
        float sq = 0.f;
#pragma unroll
        for (int q = 0; q < 16; ++q) {
            float4 c4 = qp[q];
            float vv[4] = {c4.x, c4.y, c4.z, c4.w};
#pragma unroll
            for (int j = 0; j < 4; ++j) {
                int d = 4 * q + j;
                float df = vv[j] - zr[d];
                sq = fmaf(df, df, sq);
                out[obase + d * HW2] = vv[j];
            }
        }
#pragma unroll
        for (int m = 1; m < 64; m <<= 1) sq += __shfl_xor(sq, m, 64);
        if (lane == 0) atomicAdd(lossAcc, (double)sq);
    }
}

// ---------------- loss + perplexity ----------------
__global__ void finalizeK(const int* __restrict__ counts,
                          const double* __restrict__ lossAcc,
                          float* __restrict__ out)
{
    const int tid = threadIdx.x;
    double ent = 0.0;
    for (int k = tid; k < 512; k += 64) {
        double p = (double)counts[k] / NPX;
        ent -= p * log(p + 1e-10);
    }
#pragma unroll
    for (int m = 1; m < 64; m <<= 1) ent += __shfl_xor(ent, m, 64);
    if (tid == 0) {
        out[SYM_N]     = (float)(1.25 * lossAcc[0] / (double)SYM_N);
        out[SYM_N + 1] = (float)exp(ent);
    }
}

// ---------------- fallback: zero + sentinel ----------------
__global__ __launch_bounds__(256) void zeroOutK(float* __restrict__ out, int n) {
    int i = blockIdx.x * 256 + threadIdx.x;
    if (i < n) out[i] = 0.0f;
}
__global__ void sentinelK(float* out, float lossv, float perpv) {
    if (threadIdx.x == 0) { out[SYM_N] = lossv; out[SYM_N + 1] = perpv; }
}

// =======================================================================
// primary path: conv1 legacy fp32 -> h1 fp16 -> MFMA conv2/conv3
// ws layout: header 64K | R1 = 128MB region (y1 fp32; reused: y2h fp16 @+0,
// y3 fp32 @+32M, z @+64M, w2s @+72M, w3s @+72.25M) | h1 fp16 64MB
// =======================================================================
static void run_mfma(void* const* d_in, float* out, char* ws, hipStream_t stream)
{
    const float* x   = (const float*)d_in[0];
    const float* w1  = (const float*)d_in[1];
    const float* b1  = (const float*)d_in[2];
    const float* g1  = (const float*)d_in[3];
    const float* be1 = (const float*)d_in[4];
    const float* w2  = (const float*)d_in[5];
    const float* b2  = (const float*)d_in[6];
    const float* g2  = (const float*)d_in[7];
    const float* be2 = (const float*)d_in[8];
    const float* w3  = (const float*)d_in[9];
    const float* b3  = (const float*)d_in[10];
    const float* g3  = (const float*)d_in[11];
    const float* be3 = (const float*)d_in[12];
    const float* wq  = (const float*)d_in[13];
    const float* bq  = (const float*)d_in[14];
    const float* cb  = (const float*)d_in[15];

    double* statd  = (double*)(ws);
    float*  sscale = (float*)(ws + 16384);
    int*    counts = (int*)(ws + 24576);
    float*  csqf   = (float*)(ws + 28672);
    double* csqd   = (double*)(ws + 30720);
    int*    kbord  = (int*)(ws + 34816);
    double* lossAcc = statd + 1536;

    char* R1 = ws + 65536;
    float*     y1  = (float*)R1;
    _Float16*  y2h = (_Float16*)R1;                              // reuses y1 (dead)
    float*     y3  = (float*)(R1 + 33554432ull);
    float*     z   = (float*)(R1 + 67108864ull);
    _Float16*  w2s = (_Float16*)(R1 + 75497472ull);
    _Float16*  w3s = (_Float16*)(R1 + 75759616ull);
    _Float16*  h1  = (_Float16*)(ws + 65536ull + 134217728ull);

    initStatsK<<<7, 256, 0, stream>>>(statd, counts);
    csqK<<<2, 256, 0, stream>>>(cb, csqf, csqd);
    borderK<<<1, 512, 0, stream>>>(csqd, kbord, counts, lossAcc);
    fillK<<<(SYM_N + 255) / 256, 256, 0, stream>>>(kbord, cb, out);

    // conv1 (legacy fp32) -> y1 + stats1
    conv4x4s2K<3, 64, 256, 256, false, true, true, float, float>
        <<<dim3(128, 1, BATCH), 256, 0, stream>>>(
        x, w1, b1, nullptr, nullptr, y1, statd + 0, statd + 256);
    bnFinK<<<1, 256, 0, stream>>>(statd + 0, statd + 256, g1, be1,
                                  sscale + 0, sscale + 256, 64, 524288.0);
    // h1 = fp16(relu(bn1(y1)))  [y1 dead afterwards]
    bnApplyK<<<32768, 256, 0, stream>>>(y1, sscale + 0, sscale + 256, h1);
    // weight repacks (into dead y1 region)
    splitWK<<<512, 256, 0, stream>>>(w2, w2s, 64, 128);
    splitWK<<<2048, 256, 0, stream>>>(w3, w3s, 128, 256);

    // conv2 MFMA: h1 -> y2h (raw conv+bias, fp16) + stats2
    convMfmaK<64, 128, 128, 2, false, _Float16>
        <<<dim3(32, 1, BATCH), 512, 0, stream>>>(
        h1, w2s, b2, nullptr, nullptr, y2h, statd + 512, statd + 768);
    bnFinK<<<1, 256, 0, stream>>>(statd + 512, statd + 768, g2, be2,
                                  sscale + 512, sscale + 768, 128, 131072.0);

    // conv3 MFMA: bn2+relu(y2h) -> y3 (fp32) + stats3
    convMfmaK<128, 256, 64, 4, true, float>
        <<<dim3(8, 1, BATCH), 512, 0, stream>>>(
        y2h, w3s, b3, sscale + 512, sscale + 768, y3, statd + 1024, statd + 1280);
    bnFinK<<<1, 256, 0, stream>>>(statd + 1024, statd + 1280, g3, be3,
                                  sscale + 1024, sscale + 1280, 256, 32768.0);

    convqK<<<256, 128, 0, stream>>>(y3, wq, bq, sscale + 1024, sscale + 1280, z);
    vqK<<<512, 256, 0, stream>>>(z, cb, csqf, out, counts, lossAcc);
    finalizeK<<<1, 64, 0, stream>>>(counts, lossAcc, out);
}

// =======================================================================
// fallback tier2: single-pass bf16 storage (proven structure)
// =======================================================================
static void run_fast_bf16(void* const* d_in, float* out, char* ws, hipStream_t stream)
{
    const float* x   = (const float*)d_in[0];
    const float* w1  = (const float*)d_in[1];
    const float* b1  = (const float*)d_in[2];
    const float* g1  = (const float*)d_in[3];
    const float* be1 = (const float*)d_in[4];
    const float* w2  = (const float*)d_in[5];
    const float* b2  = (const float*)d_in[6];
    const float* g2  = (const float*)d_in[7];
    const float* be2 = (const float*)d_in[8];
    const float* w3  = (const float*)d_in[9];
    const float* b3  = (const float*)d_in[10];
    const float* g3  = (const float*)d_in[11];
    const float* be3 = (const float*)d_in[12];
    const float* wq  = (const float*)d_in[13];
    const float* bq  = (const float*)d_in[14];
    const float* cb  = (const float*)d_in[15];

    double* statd  = (double*)(ws);
    float*  sscale = (float*)(ws + 16384);
    int*    counts = (int*)(ws + 24576);
    float*  csqf   = (float*)(ws + 28672);
    double* csqd   = (double*)(ws + 30720);
    int*    kbord  = (int*)(ws + 34816);
    double* lossAcc = statd + 1536;

    __hip_bfloat16* y1 = (__hip_bfloat16*)(ws + 65536);
    __hip_bfloat16* y2 = (__hip_bfloat16*)(ws + 65536 + 67108864ull);
    float* y3 = (float*)(ws + 65536);
    float* z  = (float*)(ws + 65536 + 33554432ull);

    initStatsK<<<7, 256, 0, stream>>>(statd, counts);
    csqK<<<2, 256, 0, stream>>>(cb, csqf, csqd);
    borderK<<<1, 512, 0, stream>>>(csqd, kbord, counts, lossAcc);
    fillK<<<(SYM_N + 255) / 256, 256, 0, stream>>>(kbord, cb, out);

    conv4x4s2K<3, 64, 256, 256, false, true, true, float, __hip_bfloat16>
        <<<dim3(128, 1, BATCH), 256, 0, stream>>>(
        x, w1, b1, nullptr, nullptr, y1, statd + 0, statd + 256);
    bnFinK<<<1, 256, 0, stream>>>(statd + 0, statd + 256, g1, be1,
                                  sscale + 0, sscale + 256, 64, 524288.0);

    conv8K<64, 128, 128, 128, 8, 32, true, true, true, __hip_bfloat16, __hip_bfloat16>
        <<<dim3(16, 2, BATCH), 256, 0, stream>>>(
        y1, w2, b2, sscale + 0, sscale + 256, y2, statd + 512, statd + 768);
    bnFinK<<<1, 256, 0, stream>>>(statd + 512, statd + 768, g2, be2,
                                  sscale + 512, sscale + 768, 128, 131072.0);

    conv8K<128, 256, 64, 64, 16, 16, true, true, true, __hip_bfloat16, float>
        <<<dim3(4, 4, BATCH), 256, 0, stream>>>(
        y2, w3, b3, sscale + 512, sscale + 768, y3, statd + 1024, statd + 1280);
    bnFinK<<<1, 256, 0, stream>>>(statd + 1024, statd + 1280, g3, be3,
                                  sscale + 1024, sscale + 1280, 256, 32768.0);

    convqK<<<256, 128, 0, stream>>>(y3, wq, bq, sscale + 1024, sscale + 1280, z);
    vqK<<<512, 256, 0, stream>>>(z, cb, csqf, out, counts, lossAcc);
    finalizeK<<<1, 64, 0, stream>>>(counts, lossAcc, out);
}

extern "C" void kernel_launch(void* const* d_in, const int* in_sizes, int n_in,
                              void* d_out, int out_size, void* d_ws, size_t ws_size,
                              hipStream_t stream)
{
    float* out = (float*)d_out;
    char* ws = (char*)d_ws;

    if (ws_size >= NEED1) {
        run_mfma(d_in, out, ws, stream);
    } else if (ws_size >= NEED2) {
        run_fast_bf16(d_in, out, ws, stream);
    } else {
        zeroOutK<<<(SYM_N + 2 + 255) / 256, 256, 0, stream>>>(out, SYM_N + 2);
        sentinelK<<<1, 64, 0, stream>>>(out, -4444.0f, -5555.0f);
    }
}

// Round 11
// 638.272 us; speedup vs baseline: 5.0058x; 1.1547x over previous
//
#include <hip/hip_runtime.h>
#include <hip/hip_bf16.h>

// SymbolicEncoder: conv(3->64,s2)+BN+ReLU -> conv(64->128,s2)+BN+ReLU ->
// conv(128->256,s2)+BN+ReLU -> 1x1 conv(256->64, padding (1,1)) -> VQ.
// z is (32,64,34,34); border px have z = bq = 0.
// Output (fp32 flat): symbols @ [0:2367488], loss @ 2367488, perp @ 2367489.
//
// R11: conv1 stores fp16 raw via the 8co x 8px tile (single 3-ci chunk);
// BN1+ReLU fused into conv2's MFMA A-staging (bnApplyK removed).

#define BATCH 32

#define SYM_N 2367488
#define NPX   36992.0
#define CHW   73984
#define HW2   1156

static const unsigned long long NEED1 = 201392128ull;
static const unsigned long long NEED2 = 100728832ull;

typedef _Float16 half8 __attribute__((ext_vector_type(8)));
typedef float f32x16 __attribute__((ext_vector_type(16)));

__device__ __forceinline__ float ldv(const float* p) { return *p; }
__device__ __forceinline__ float ldv(const __hip_bfloat16* p) { return __bfloat162float(*p); }
__device__ __forceinline__ float ldv(const _Float16* p) { return (float)(*p); }
__device__ __forceinline__ void stv(float* p, float v) { *p = v; }
__device__ __forceinline__ void stv(__hip_bfloat16* p, float v) { *p = __float2bfloat16(v); }
__device__ __forceinline__ void stv(_Float16* p, float v) { *p = (_Float16)v; }

__device__ __forceinline__ void st4(float* p, float a, float b, float c, float d) {
    float4 v; v.x = a; v.y = b; v.z = c; v.w = d;
    *(float4*)p = v;
}
__device__ __forceinline__ void st4(_Float16* p, float a, float b, float c, float d) {
    union { _Float16 h[4]; ushort4 u; } t;
    t.h[0] = (_Float16)a; t.h[1] = (_Float16)b; t.h[2] = (_Float16)c; t.h[3] = (_Float16)d;
    *(ushort4*)p = t.u;
}

// ---------------- init ----------------
__global__ void initStatsK(double* statd, int* counts) {
    int i = threadIdx.x + blockIdx.x * blockDim.x;
    if (i < 1537) statd[i] = 0.0;
    if (i < 512) counts[i] = 0;
}

// ---------------- codebook squared norms ----------------
__global__ void csqK(const float* __restrict__ cb, float* __restrict__ csqf,
                     double* __restrict__ csqd) {
    int k = threadIdx.x + blockIdx.x * blockDim.x;
    if (k < 512) {
        const float* r = cb + (size_t)k * 64;
        float s = 0.f; double sd = 0.0;
        for (int d = 0; d < 64; ++d) {
            s = fmaf(r[d], r[d], s);
            sd += (double)r[d] * (double)r[d];
        }
        csqf[k] = s; csqd[k] = sd;
    }
}

// ---------------- border codeword ----------------
__global__ void borderK(const double* __restrict__ csqd, int* __restrict__ kborder,
                        int* __restrict__ counts, double* __restrict__ lossAcc) {
    __shared__ double sV[512];
    __shared__ int sI[512];
    const int t = threadIdx.x;
    sV[t] = csqd[t]; sI[t] = t;
    __syncthreads();
    for (int st = 256; st > 0; st >>= 1) {
        if (t < st) {
            double v2 = sV[t + st]; int i2 = sI[t + st];
            if (v2 < sV[t] || (v2 == sV[t] && i2 < sI[t])) { sV[t] = v2; sI[t] = i2; }
        }
        __syncthreads();
    }
    if (t == 0) {
        int k = sI[0];
        *kborder = k;
        atomicAdd(&counts[k], 4224);
        atomicAdd(lossAcc, 4224.0 * sV[0]);
    }
}

// ---------------- fill symbols with border codeword ----------------
__global__ __launch_bounds__(256) void fillK(const int* __restrict__ kborder,
                                             const float* __restrict__ cb,
                                             float* __restrict__ out) {
    const int kb = *kborder;
    int E = blockIdx.x * 256 + threadIdx.x;
    if (E < SYM_N) {
        int d = (E / HW2) & 63;
        out[E] = cb[(size_t)kb * 64 + d];
    }
}

// ---------------- legacy conv 4x4 s2 (tier2 fallback conv1) ----------------
template<int CIN, int COUT, int IH, int IW, bool BN_IN, bool STORE, bool STATS,
         typename TI, typename TO>
__global__ __launch_bounds__(256) void conv4x4s2K(
    const TI* __restrict__ in, const float* __restrict__ wgt,
    const float* __restrict__ bias,
    const float* __restrict__ inScale, const float* __restrict__ inShift,
    TO* __restrict__ out, double* __restrict__ gSum, double* __restrict__ gSq)
{
    constexpr int OH = IH / 2, OW = IW / 2;
    constexpr int COLB = OW / 16;
    __shared__ float sIn[8 * 18 * 34];
    __shared__ float sW[128 * 64];
    __shared__ float sStat[128];

    const int tid = threadIdx.x;
    const int tx = tid & 15, ty = tid >> 4;
    const int cog = ty & 7, rg = ty >> 3;
    const int n = blockIdx.z;
    const int coBase = blockIdx.y * 64;
    const int brow = blockIdx.x / COLB, bcol = blockIdx.x % COLB;
    const int oh0 = brow * 8, ow0 = bcol * 16;
    const int ihb = oh0 * 2 - 1, iwb = ow0 * 2 - 1;

    float acc[8][4];
#pragma unroll
    for (int j = 0; j < 8; ++j)
#pragma unroll
        for (int r = 0; r < 4; ++r) acc[j][r] = 0.f;

    for (int c0 = 0; c0 < CIN; c0 += 8) {
        const int CC = (CIN - c0 < 8) ? (CIN - c0) : 8;
        for (int i = tid; i < 8 * 18 * 34; i += 256) {
            int ci = i / 612; int rem = i - ci * 612;
            int ih = rem / 34; int iw = rem - ih * 34;
            float v = 0.f;
            int gh = ihb + ih, gw = iwb + iw;
            if (ci < CC && (unsigned)gh < (unsigned)IH && (unsigned)gw < (unsigned)IW) {
                float r0 = ldv(&in[(((size_t)n * CIN + (c0 + ci)) * IH + gh) * IW + gw]);
                if (BN_IN) r0 = fmaxf(fmaf(r0, inScale[c0 + ci], inShift[c0 + ci]), 0.f);
                v = r0;
            }
            sIn[i] = v;
        }
        for (int i = tid; i < 8192; i += 256) {
            int co = i >> 7, r = i & 127;
            int ci = r >> 4, t = r & 15;
            float v = 0.f;
            if (ci < CC) v = wgt[(((size_t)(coBase + co)) * CIN + (c0 + ci)) * 16 + t];
            sW[r * 64 + (co ^ ((r & 7) << 3))] = v;
        }
        __syncthreads();
        for (int ci = 0; ci < CC; ++ci) {
#pragma unroll
            for (int kh = 0; kh < 4; ++kh) {
#pragma unroll
                for (int kw = 0; kw < 4; ++kw) {
                    const int tap = kh * 4 + kw;
                    const float* wp = sW + (ci * 16 + tap) * 64 + ((cog * 8) ^ ((tap & 7) << 3));
                    float4 wa = *(const float4*)wp;
                    float4 wb = *(const float4*)(wp + 4);
                    const float* ip = sIn + (ci * 18 + rg * 8 + kh) * 34 + tx * 2 + kw;
                    float wv[8] = {wa.x, wa.y, wa.z, wa.w, wb.x, wb.y, wb.z, wb.w};
                    float iv[4] = {ip[0], ip[68], ip[136], ip[204]};
#pragma unroll
                    for (int j = 0; j < 8; ++j)
#pragma unroll
                        for (int r = 0; r < 4; ++r)
                            acc[j][r] = fmaf(wv[j], iv[r], acc[j][r]);
                }
            }
        }
        __syncthreads();
    }

    if (STATS) {
        if (tid < 128) sStat[tid] = 0.f;
        __syncthreads();
    }

    const int coG = coBase + cog * 8;
#pragma unroll
    for (int j = 0; j < 8; ++j) {
        float bv = bias[coG + j];
        float s = 0.f, s2 = 0.f;
#pragma unroll
        for (int r = 0; r < 4; ++r) {
            float v = acc[j][r] + bv;
            if (STORE)
                stv(&out[(((size_t)n * COUT + coG + j) * OH + (oh0 + rg * 4 + r)) * OW + ow0 + tx], v);
            s += v; s2 = fmaf(v, v, s2);
        }
        if (STATS) {
#pragma unroll
            for (int m = 1; m < 16; m <<= 1) {
                s  += __shfl_xor(s, m, 64);
                s2 += __shfl_xor(s2, m, 64);
            }
            if (tx == 0) {
                atomicAdd(&sStat[cog * 8 + j], s);
                atomicAdd(&sStat[64 + cog * 8 + j], s2);
            }
        }
    }
    if (STATS) {
        __syncthreads();
        if (tid < 64) {
            atomicAdd(&gSum[coBase + tid], (double)sStat[tid]);
            atomicAdd(&gSq[coBase + tid],  (double)sStat[64 + tid]);
        }
    }
}

// ---------------- conv 4x4 s2, 8co x 8px tile (conv1 primary + tier2) --------
template<int CIN, int COUT, int IH, int IW, int TH, int TW, bool BN_IN,
         bool STORE, bool STATS, typename TI, typename TO>
__global__ __launch_bounds__(256, 3) void conv8K(
    const TI* __restrict__ in, const float* __restrict__ wgt,
    const float* __restrict__ bias,
    const float* __restrict__ inScale, const float* __restrict__ inShift,
    TO* __restrict__ out, double* __restrict__ gSum, double* __restrict__ gSq)
{
    constexpr int OH = IH / 2, OW = IW / 2;
    constexpr int COLB = OW / TW;
    constexpr int SW = TW / 2;
    constexpr int ITH = TH * 2 + 2;
    constexpr int ITWP = TW * 2 + 4;
    constexpr int INSZ = 4 * ITH * ITWP;

    __shared__ float sIn[INSZ];
    __shared__ float sW[4 * 16 * 64];
    __shared__ float sStat[128];

    const int tid = threadIdx.x;
    const int s = tid & 31, cog = tid >> 5;
    const int sw = s & (SW - 1), sh = s / SW;
    const int n = blockIdx.z;
    const int coBase = blockIdx.y * 64;
    const int brow = blockIdx.x / COLB, bcol = blockIdx.x % COLB;
    const int oh0 = brow * TH, ow0 = bcol * TW;
    const int ihb = oh0 * 2 - 1, iwb = ow0 * 2 - 1;

    float acc[8][8];
#pragma unroll
    for (int c = 0; c < 8; ++c)
#pragma unroll
        for (int p = 0; p < 8; ++p) acc[c][p] = 0.f;

    for (int c0 = 0; c0 < CIN; c0 += 4) {
        const int CC = (CIN - c0 < 4) ? (CIN - c0) : 4;
        for (int i = tid; i < INSZ; i += 256) {
            int ci = i / (ITH * ITWP); int rem = i - ci * (ITH * ITWP);
            int ih = rem / ITWP; int iw = rem - ih * ITWP;
            float v = 0.f;
            int gh = ihb + ih, gw = iwb + iw;
            if (ci < CC && (unsigned)gh < (unsigned)IH && (unsigned)gw < (unsigned)IW) {
                float r0 = ldv(&in[(((size_t)n * CIN + (c0 + ci)) * IH + gh) * IW + gw]);
                if (BN_IN) r0 = fmaxf(fmaf(r0, inScale[c0 + ci], inShift[c0 + ci]), 0.f);
                v = r0;
            }
            sIn[i] = v;
        }
        for (int i = tid; i < 4096; i += 256) {
            int r = i >> 6, co = i & 63;
            int ci = r >> 4, tap = r & 15;
            float v = (ci < CC) ? wgt[(((size_t)(coBase + co)) * CIN + (c0 + ci)) * 16 + tap] : 0.f;
            sW[r * 64 + co] = v;
        }
        __syncthreads();
        for (int ci = 0; ci < CC; ++ci) {
#pragma unroll
            for (int kh = 0; kh < 4; ++kh) {
                float inv[4][8];
#pragma unroll
                for (int r = 0; r < 4; ++r) {
                    const float* ip = sIn + (ci * ITH + (sh * 4 + r) * 2 + kh) * ITWP + sw * 4;
                    float4 a = *(const float4*)ip;
                    float4 b = *(const float4*)(ip + 4);
                    inv[r][0] = a.x; inv[r][1] = a.y; inv[r][2] = a.z; inv[r][3] = a.w;
                    inv[r][4] = b.x; inv[r][5] = b.y; inv[r][6] = b.z; inv[r][7] = b.w;
                }
#pragma unroll
                for (int kw = 0; kw < 4; ++kw) {
                    const float* wp = sW + (ci * 16 + kh * 4 + kw) * 64 + cog * 8;
                    float4 wa = *(const float4*)wp;
                    float4 wb = *(const float4*)(wp + 4);
                    float wv[8] = {wa.x, wa.y, wa.z, wa.w, wb.x, wb.y, wb.z, wb.w};
#pragma unroll
                    for (int c = 0; c < 8; ++c)
#pragma unroll
                        for (int r = 0; r < 4; ++r)
#pragma unroll
                            for (int j = 0; j < 2; ++j)
                                acc[c][r * 2 + j] =
                                    fmaf(wv[c], inv[r][2 * j + kw], acc[c][r * 2 + j]);
                }
            }
        }
        __syncthreads();
    }

    if (STATS) {
        if (tid < 128) sStat[tid] = 0.f;
        __syncthreads();
    }

    const int coG = coBase + cog * 8;
#pragma unroll
    for (int c = 0; c < 8; ++c) {
        float bv = bias[coG + c];
        float s1 = 0.f, s2 = 0.f;
#pragma unroll
        for (int p = 0; p < 8; ++p) {
            float v = acc[c][p] + bv;
            int oh = oh0 + sh * 4 + (p >> 1), ow = ow0 + sw * 2 + (p & 1);
            if (STORE)
                stv(&out[(((size_t)n * COUT + coG + c) * OH + oh) * OW + ow], v);
            s1 += v; s2 = fmaf(v, v, s2);
        }
        if (STATS) {
#pragma unroll
            for (int m = 1; m < 32; m <<= 1) {
                s1 += __shfl_xor(s1, m, 64);
                s2 += __shfl_xor(s2, m, 64);
            }
            if ((tid & 31) == 0) {
                atomicAdd(&sStat[cog * 8 + c], s1);
                atomicAdd(&sStat[64 + cog * 8 + c], s2);
            }
        }
    }
    if (STATS) {
        __syncthreads();
        if (tid < 64) {
            atomicAdd(&gSum[coBase + tid], (double)sStat[tid]);
            atomicAdd(&gSq[coBase + tid],  (double)sStat[64 + tid]);
        }
    }
}

// ---------------- BN finalize ----------------
__global__ void bnFinK(const double* __restrict__ gSum, const double* __restrict__ gSq,
                       const float* __restrict__ g, const float* __restrict__ be,
                       float* __restrict__ scale, float* __restrict__ shift,
                       int C, double cnt)
{
    int c = threadIdx.x;
    if (c < C) {
        double m = gSum[c] / cnt;
        double v = gSq[c] / cnt - m * m;
        double sc = (double)g[c] / sqrt(v + 1e-5);
        scale[c] = (float)sc;
        shift[c] = (float)((double)be[c] - m * sc);
    }
}

// ---------------- weight repack: [co][ci][tap] f32 -> [tap][chunk][co][16] f16 ----
__global__ __launch_bounds__(256) void splitWK(
    const float* __restrict__ w, _Float16* __restrict__ wsOut, int CIN, int COUT)
{
    int CH = CIN >> 4;
    int total = 16 * CH * COUT * 16;
    for (int i = blockIdx.x * 256 + threadIdx.x; i < total; i += gridDim.x * 256) {
        int cil = i & 15; int r = i >> 4;
        int co = r % COUT; r /= COUT;
        int c = r % CH; int tap = r / CH;
        int ci = c * 16 + cil;
        wsOut[i] = (_Float16)w[((size_t)co * CIN + ci) * 16 + tap];
    }
}

// ---------------- MFMA conv 4x4 s2 (implicit GEMM per tap) ----------------
template<int CIN, int COUT, int IH, int NF, bool BN_IN, typename TO>
__global__ __launch_bounds__(512) void convMfmaK(
    const _Float16* __restrict__ in, const _Float16* __restrict__ wsplit,
    const float* __restrict__ bias,
    const float* __restrict__ inScale, const float* __restrict__ inShift,
    TO* __restrict__ out, double* __restrict__ gSum, double* __restrict__ gSq)
{
    constexpr int OH = IH / 2;
    constexpr int OWB = OH / 32;
    constexpr int CH = CIN / 16;
    __shared__ _Float16 sA[10 * 68 * 24];
    __shared__ float sStat[2 * COUT];

    const int tid = threadIdx.x;
    const int l = tid & 63, wid = tid >> 6;
    const int lane31 = l & 31, hs = l >> 5;
    const int mw = wid & 3, nw = wid >> 2;
    const int n = blockIdx.z;
    const int ohB = (blockIdx.x / OWB) * 4;
    const int owB = (blockIdx.x % OWB) * 32;
    const int ghBase = 2 * ohB - 1, gwBase = 2 * owB - 1;

    for (int i = tid; i < 2 * COUT; i += 512) sStat[i] = 0.f;

    f32x16 acc[NF];
#pragma unroll
    for (int f = 0; f < NF; ++f)
#pragma unroll
        for (int j = 0; j < 16; ++j) acc[f][j] = 0.f;

    for (int c = 0; c < CH; ++c) {
        __syncthreads();
        for (int i = tid; i < 10 * 68 * 16; i += 512) {
            int iw = i % 68; int r = i / 68; int ih = r % 10; int cil = r / 10;
            int gh = ghBase + ih, gw = gwBase + iw;
            float v = 0.f;
            if ((unsigned)gh < (unsigned)IH && (unsigned)gw < (unsigned)IH) {
                v = (float)in[(((size_t)n * CIN + c * 16 + cil) * IH + gh) * IH + gw];
                if (BN_IN) v = fmaxf(fmaf(v, inScale[c * 16 + cil], inShift[c * 16 + cil]), 0.f);
            }
            sA[(ih * 68 + iw) * 24 + cil] = (_Float16)v;
        }
        __syncthreads();
#pragma unroll
        for (int kh = 0; kh < 4; ++kh) {
#pragma unroll
            for (int kw = 0; kw < 4; ++kw) {
                const int ihX = 2 * mw + kh;
                half8 a = *(const half8*)&sA[(ihX * 68 + 2 * lane31 + kw) * 24 + hs * 8];
                const _Float16* bp = wsplit
                    + (((size_t)(kh * 4 + kw) * CH + c) * COUT + nw * (NF * 32) + lane31) * 16
                    + hs * 8;
#pragma unroll
                for (int f = 0; f < NF; ++f) {
                    half8 b = *(const half8*)(bp + (size_t)f * 32 * 16);
                    acc[f] = __builtin_amdgcn_mfma_f32_32x32x16_f16(a, b, acc[f], 0, 0, 0);
                }
            }
        }
    }

    const int oh = ohB + mw;
#pragma unroll
    for (int f = 0; f < NF; ++f) {
        int co = nw * (NF * 32) + f * 32 + lane31;
        float bv = bias[co];
        float s1 = 0.f, s2 = 0.f;
#pragma unroll
        for (int q = 0; q < 4; ++q) {
            float v0 = acc[f][q * 4 + 0] + bv;
            float v1 = acc[f][q * 4 + 1] + bv;
            float v2 = acc[f][q * 4 + 2] + bv;
            float v3 = acc[f][q * 4 + 3] + bv;
            s1 += (v0 + v1) + (v2 + v3);
            s2 = fmaf(v0, v0, s2); s2 = fmaf(v1, v1, s2);
            s2 = fmaf(v2, v2, s2); s2 = fmaf(v3, v3, s2);
            int ow = owB + q * 8 + hs * 4;
            st4(&out[(((size_t)n * COUT + co) * OH + oh) * OH + ow], v0, v1, v2, v3);
        }
        s1 += __shfl_xor(s1, 32, 64);
        s2 += __shfl_xor(s2, 32, 64);
        if (hs == 0) {
            atomicAdd(&sStat[co], s1);
            atomicAdd(&sStat[COUT + co], s2);
        }
    }
    __syncthreads();
    for (int i = tid; i < COUT; i += 512) {
        atomicAdd(&gSum[i], (double)sStat[i]);
        atomicAdd(&gSq[i],  (double)sStat[COUT + i]);
    }
}

// ---------------- 1x1 conv (interior px) with fused BN3+ReLU ----------------
__global__ __launch_bounds__(128) void convqK(
    const float* __restrict__ y3, const float* __restrict__ wq,
    const float* __restrict__ bq,
    const float* __restrict__ sc3, const float* __restrict__ sh3,
    float* __restrict__ z)
{
    __shared__ float sWq[64 * 68];
    __shared__ float sS[64], sH[64];
    const int tid = threadIdx.x;
    const int px = blockIdx.x * 128 + tid;
    const int n = px >> 10, hw = px & 1023;

    float accv[64];
#pragma unroll
    for (int d = 0; d < 64; ++d) accv[d] = 0.f;

    const float* base = y3 + (((size_t)n * 256) << 10) + hw;
    for (int c0 = 0; c0 < 256; c0 += 64) {
        __syncthreads();
        for (int i = tid; i < 4096; i += 128) {
            int c = i & 63, d = i >> 6;
            sWq[c * 68 + d] = wq[(size_t)d * 256 + c0 + c];
        }
        if (tid < 64) { sS[tid] = sc3[c0 + tid]; sH[tid] = sh3[c0 + tid]; }
        __syncthreads();
        for (int c = 0; c < 64; ++c) {
            float h = base[(size_t)(c0 + c) << 10];
            h = fmaxf(fmaf(h, sS[c], sH[c]), 0.f);
            const float4* wrow = (const float4*)(sWq + c * 68);
#pragma unroll
            for (int q = 0; q < 16; ++q) {
                float4 w4 = wrow[q];
                accv[4*q+0] = fmaf(h, w4.x, accv[4*q+0]);
                accv[4*q+1] = fmaf(h, w4.y, accv[4*q+1]);
                accv[4*q+2] = fmaf(h, w4.z, accv[4*q+2]);
                accv[4*q+3] = fmaf(h, w4.w, accv[4*q+3]);
            }
        }
    }
    float* zo = z + (size_t)px * 64;
    const float4* bq4 = (const float4*)bq;
#pragma unroll
    for (int q = 0; q < 16; ++q) {
        float4 b4 = bq4[q];
        float4 v;
        v.x = accv[4*q+0] + b4.x; v.y = accv[4*q+1] + b4.y;
        v.z = accv[4*q+2] + b4.z; v.w = accv[4*q+3] + b4.w;
        ((float4*)zo)[q] = v;
    }
}

// ---------------- vector quantize ----------------
__global__ __launch_bounds__(256) void vqK(
    const float* __restrict__ z, const float* __restrict__ cb,
    const float* __restrict__ csqf, float* __restrict__ out,
    int* __restrict__ counts, double* __restrict__ lossAcc)
{
    const int tid = threadIdx.x;
    const int lane = tid & 63;
    const int grp = tid >> 6;
    const int px = blockIdx.x * 64 + lane;

    float zr[64];
    const float4* zp = (const float4*)(z + (size_t)px * 64);
#pragma unroll
    for (int q = 0; q < 16; ++q) {
        float4 t = zp[q];
        zr[4*q] = t.x; zr[4*q+1] = t.y; zr[4*q+2] = t.z; zr[4*q+3] = t.w;
    }

    const int kbase = grp * 128;
    float best = 3.4e38f; int bidx = kbase;
    for (int kk = 0; kk < 128; ++kk) {
        const float4* crow = (const float4*)(cb + (size_t)(kbase + kk) * 64);
        float d0 = 0.f, d1 = 0.f, d2 = 0.f, d3 = 0.f;
#pragma unroll
        for (int q = 0; q < 16; ++q) {
            float4 c4 = crow[q];
            d0 = fmaf(zr[4*q+0], c4.x, d0);
            d1 = fmaf(zr[4*q+1], c4.y, d1);
            d2 = fmaf(zr[4*q+2], c4.z, d2);
            d3 = fmaf(zr[4*q+3], c4.w, d3);
        }
        float dot = (d0 + d1) + (d2 + d3);
        float score = csqf[kbase + kk] - 2.0f * dot;
        if (score < best) { best = score; bidx = kbase + kk; }
    }

    __shared__ float sB[256];
    __shared__ int   sI[256];
    sB[tid] = best; sI[tid] = bidx;
    __syncthreads();
    if (grp == 0) {
#pragma unroll
        for (int g = 1; g < 4; ++g) {
            float b = sB[lane + 64 * g]; int i = sI[lane + 64 * g];
            if (b < best || (b == best && i < bidx)) { best = b; bidx = i; }
        }
        atomicAdd(&counts[bidx], 1);

        const int n = px >> 10, hw = px & 1023;
        const int h = hw >> 5, w = hw & 31;
        const int obase = n * CHW + (h + 1) * 34 + (w + 1);
        const float4* qp = (const float4*)(cb + (size_t)bidx * 64);
        float sq = 0.f;
#pragma unroll
        for (int q = 0; q < 16; ++q) {
            float4 c4 = qp[q];
            float vv[4] = {c4.x, c4.y, c4.z, c4.w};
#pragma unroll
            for (int j = 0; j < 4; ++j) {
                int d = 4 * q + j;
                float df = vv[j] - zr[d];
                sq = fmaf(df, df, sq);
                out[obase + d * HW2] = vv[j];
            }
        }
#pragma unroll
        for (int m = 1; m < 64; m <<= 1) sq += __shfl_xor(sq, m, 64);
        if (lane == 0) atomicAdd(lossAcc, (double)sq);
    }
}

// ---------------- loss + perplexity ----------------
__global__ void finalizeK(const int* __restrict__ counts,
                          const double* __restrict__ lossAcc,
                          float* __restrict__ out)
{
    const int tid = threadIdx.x;
    double ent = 0.0;
    for (int k = tid; k < 512; k += 64) {
        double p = (double)counts[k] / NPX;
        ent -= p * log(p + 1e-10);
    }
#pragma unroll
    for (int m = 1; m < 64; m <<= 1) ent += __shfl_xor(ent, m, 64);
    if (tid == 0) {
        out[SYM_N]     = (float)(1.25 * lossAcc[0] / (double)SYM_N);
        out[SYM_N + 1] = (float)exp(ent);
    }
}

// ---------------- fallback: zero + sentinel ----------------
__global__ __launch_bounds__(256) void zeroOutK(float* __restrict__ out, int n) {
    int i = blockIdx.x * 256 + threadIdx.x;
    if (i < n) out[i] = 0.0f;
}
__global__ void sentinelK(float* out, float lossv, float perpv) {
    if (threadIdx.x == 0) { out[SYM_N] = lossv; out[SYM_N + 1] = perpv; }
}

// =======================================================================
// primary path: conv1 (8px tile, fp16 out) -> MFMA conv2 (BN1 fused) ->
// MFMA conv3 (BN2 fused) -> convq -> vq
// ws: header 64K | y1h 64MB | y2h 32MB | y3 32MB | z 8MB | w2s | w3s
// =======================================================================
static void run_mfma(void* const* d_in, float* out, char* ws, hipStream_t stream)
{
    const float* x   = (const float*)d_in[0];
    const float* w1  = (const float*)d_in[1];
    const float* b1  = (const float*)d_in[2];
    const float* g1  = (const float*)d_in[3];
    const float* be1 = (const float*)d_in[4];
    const float* w2  = (const float*)d_in[5];
    const float* b2  = (const float*)d_in[6];
    const float* g2  = (const float*)d_in[7];
    const float* be2 = (const float*)d_in[8];
    const float* w3  = (const float*)d_in[9];
    const float* b3  = (const float*)d_in[10];
    const float* g3  = (const float*)d_in[11];
    const float* be3 = (const float*)d_in[12];
    const float* wq  = (const float*)d_in[13];
    const float* bq  = (const float*)d_in[14];
    const float* cb  = (const float*)d_in[15];

    double* statd  = (double*)(ws);
    float*  sscale = (float*)(ws + 16384);
    int*    counts = (int*)(ws + 24576);
    float*  csqf   = (float*)(ws + 28672);
    double* csqd   = (double*)(ws + 30720);
    int*    kbord  = (int*)(ws + 34816);
    double* lossAcc = statd + 1536;

    char* A0 = ws + 65536;
    _Float16* y1h = (_Float16*)A0;
    _Float16* y2h = (_Float16*)(A0 + 67108864ull);
    float*    y3  = (float*)(A0 + 100663296ull);
    float*    z   = (float*)(A0 + 134217728ull);
    _Float16* w2s = (_Float16*)(A0 + 142606336ull);
    _Float16* w3s = (_Float16*)(A0 + 142868480ull);

    initStatsK<<<7, 256, 0, stream>>>(statd, counts);
    csqK<<<2, 256, 0, stream>>>(cb, csqf, csqd);
    borderK<<<1, 512, 0, stream>>>(csqd, kbord, counts, lossAcc);
    fillK<<<(SYM_N + 255) / 256, 256, 0, stream>>>(kbord, cb, out);
    splitWK<<<512, 256, 0, stream>>>(w2, w2s, 64, 128);
    splitWK<<<2048, 256, 0, stream>>>(w3, w3s, 128, 256);

    // conv1: 8px tile, single 3-ci chunk, fp16 raw out + stats1
    conv8K<3, 64, 256, 256, 8, 32, false, true, true, float, _Float16>
        <<<dim3(64, 1, BATCH), 256, 0, stream>>>(
        x, w1, b1, nullptr, nullptr, y1h, statd + 0, statd + 256);
    bnFinK<<<1, 256, 0, stream>>>(statd + 0, statd + 256, g1, be1,
                                  sscale + 0, sscale + 256, 64, 524288.0);

    // conv2 MFMA: bn1+relu(y1h) -> y2h (raw, fp16) + stats2
    convMfmaK<64, 128, 128, 2, true, _Float16>
        <<<dim3(32, 1, BATCH), 512, 0, stream>>>(
        y1h, w2s, b2, sscale + 0, sscale + 256, y2h, statd + 512, statd + 768);
    bnFinK<<<1, 256, 0, stream>>>(statd + 512, statd + 768, g2, be2,
                                  sscale + 512, sscale + 768, 128, 131072.0);

    // conv3 MFMA: bn2+relu(y2h) -> y3 (fp32) + stats3
    convMfmaK<128, 256, 64, 4, true, float>
        <<<dim3(8, 1, BATCH), 512, 0, stream>>>(
        y2h, w3s, b3, sscale + 512, sscale + 768, y3, statd + 1024, statd + 1280);
    bnFinK<<<1, 256, 0, stream>>>(statd + 1024, statd + 1280, g3, be3,
                                  sscale + 1024, sscale + 1280, 256, 32768.0);

    convqK<<<256, 128, 0, stream>>>(y3, wq, bq, sscale + 1024, sscale + 1280, z);
    vqK<<<512, 256, 0, stream>>>(z, cb, csqf, out, counts, lossAcc);
    finalizeK<<<1, 64, 0, stream>>>(counts, lossAcc, out);
}

// =======================================================================
// fallback tier2: single-pass bf16 storage (proven structure)
// =======================================================================
static void run_fast_bf16(void* const* d_in, float* out, char* ws, hipStream_t stream)
{
    const float* x   = (const float*)d_in[0];
    const float* w1  = (const float*)d_in[1];
    const float* b1  = (const float*)d_in[2];
    const float* g1  = (const float*)d_in[3];
    const float* be1 = (const float*)d_in[4];
    const float* w2  = (const float*)d_in[5];
    const float* b2  = (const float*)d_in[6];
    const float* g2  = (const float*)d_in[7];
    const float* be2 = (const float*)d_in[8];
    const float* w3  = (const float*)d_in[9];
    const float* b3  = (const float*)d_in[10];
    const float* g3  = (const float*)d_in[11];
    const float* be3 = (const float*)d_in[12];
    const float* wq  = (const float*)d_in[13];
    const float* bq  = (const float*)d_in[14];
    const float* cb  = (const float*)d_in[15];

    double* statd  = (double*)(ws);
    float*  sscale = (float*)(ws + 16384);
    int*    counts = (int*)(ws + 24576);
    float*  csqf   = (float*)(ws + 28672);
    double* csqd   = (double*)(ws + 30720);
    int*    kbord  = (int*)(ws + 34816);
    double* lossAcc = statd + 1536;

    __hip_bfloat16* y1 = (__hip_bfloat16*)(ws + 65536);
    __hip_bfloat16* y2 = (__hip_bfloat16*)(ws + 65536 + 67108864ull);
    float* y3 = (float*)(ws + 65536);
    float* z  = (float*)(ws + 65536 + 33554432ull);

    initStatsK<<<7, 256, 0, stream>>>(statd, counts);
    csqK<<<2, 256, 0, stream>>>(cb, csqf, csqd);
    borderK<<<1, 512, 0, stream>>>(csqd, kbord, counts, lossAcc);
    fillK<<<(SYM_N + 255) / 256, 256, 0, stream>>>(kbord, cb, out);

    conv4x4s2K<3, 64, 256, 256, false, true, true, float, __hip_bfloat16>
        <<<dim3(128, 1, BATCH), 256, 0, stream>>>(
        x, w1, b1, nullptr, nullptr, y1, statd + 0, statd + 256);
    bnFinK<<<1, 256, 0, stream>>>(statd + 0, statd + 256, g1, be1,
                                  sscale + 0, sscale + 256, 64, 524288.0);

    conv8K<64, 128, 128, 128, 8, 32, true, true, true, __hip_bfloat16, __hip_bfloat16>
        <<<dim3(16, 2, BATCH), 256, 0, stream>>>(
        y1, w2, b2, sscale + 0, sscale + 256, y2, statd + 512, statd + 768);
    bnFinK<<<1, 256, 0, stream>>>(statd + 512, statd + 768, g2, be2,
                                  sscale + 512, sscale + 768, 128, 131072.0);

    conv8K<128, 256, 64, 64, 16, 16, true, true, true, __hip_bfloat16, float>
        <<<dim3(4, 4, BATCH), 256, 0, stream>>>(
        y2, w3, b3, sscale + 512, sscale + 768, y3, statd + 1024, statd + 1280);
    bnFinK<<<1, 256, 0, stream>>>(statd + 1024, statd + 1280, g3, be3,
                                  sscale + 1024, sscale + 1280, 256, 32768.0);

    convqK<<<256, 128, 0, stream>>>(y3, wq, bq, sscale + 1024, sscale + 1280, z);
    vqK<<<512, 256, 0, stream>>>(z, cb, csqf, out, counts, lossAcc);
    finalizeK<<<1, 64, 0, stream>>>(counts, lossAcc, out);
}

extern "C" void kernel_launch(void* const* d_in, const int* in_sizes, int n_in,
                              void* d_out, int out_size, void* d_ws, size_t ws_size,
                              hipStream_t stream)
{
    float* out = (float*)d_out;
    char* ws = (char*)d_ws;

    if (ws_size >= NEED1) {
        run_mfma(d_in, out, ws, stream);
    } else if (ws_size >= NEED2) {
        run_fast_bf16(d_in, out, ws, stream);
    } else {
        zeroOutK<<<(SYM_N + 2 + 255) / 256, 256, 0, stream>>>(out, SYM_N + 2);
        sentinelK<<<1, 64, 0, stream>>>(out, -4444.0f, -5555.0f);
    }
}

// Round 12
// 598.435 us; speedup vs baseline: 5.3390x; 1.0666x over previous
//
#include <hip/hip_runtime.h>
#include <hip/hip_bf16.h>

// SymbolicEncoder: conv(3->64,s2)+BN+ReLU -> conv(64->128,s2)+BN+ReLU ->
// conv(128->256,s2)+BN+ReLU -> 1x1 conv(256->64, padding (1,1)) -> VQ.
// z is (32,64,34,34); border px have z = bq = 0.
// Output (fp32 flat): symbols @ [0:2367488], loss @ 2367488, perp @ 2367489.
//
// R12: convq + vq fused into headK (one kernel, z never leaves the block).

#define BATCH 32

#define SYM_N 2367488
#define NPX   36992.0
#define CHW   73984
#define HW2   1156

static const unsigned long long NEED1 = 201392128ull;
static const unsigned long long NEED2 = 100728832ull;

typedef _Float16 half8 __attribute__((ext_vector_type(8)));
typedef float f32x16 __attribute__((ext_vector_type(16)));

__device__ __forceinline__ float ldv(const float* p) { return *p; }
__device__ __forceinline__ float ldv(const __hip_bfloat16* p) { return __bfloat162float(*p); }
__device__ __forceinline__ float ldv(const _Float16* p) { return (float)(*p); }
__device__ __forceinline__ void stv(float* p, float v) { *p = v; }
__device__ __forceinline__ void stv(__hip_bfloat16* p, float v) { *p = __float2bfloat16(v); }
__device__ __forceinline__ void stv(_Float16* p, float v) { *p = (_Float16)v; }

__device__ __forceinline__ void st4(float* p, float a, float b, float c, float d) {
    float4 v; v.x = a; v.y = b; v.z = c; v.w = d;
    *(float4*)p = v;
}
__device__ __forceinline__ void st4(_Float16* p, float a, float b, float c, float d) {
    union { _Float16 h[4]; ushort4 u; } t;
    t.h[0] = (_Float16)a; t.h[1] = (_Float16)b; t.h[2] = (_Float16)c; t.h[3] = (_Float16)d;
    *(ushort4*)p = t.u;
}

// ---------------- init ----------------
__global__ void initStatsK(double* statd, int* counts) {
    int i = threadIdx.x + blockIdx.x * blockDim.x;
    if (i < 1537) statd[i] = 0.0;
    if (i < 512) counts[i] = 0;
}

// ---------------- codebook squared norms ----------------
__global__ void csqK(const float* __restrict__ cb, float* __restrict__ csqf,
                     double* __restrict__ csqd) {
    int k = threadIdx.x + blockIdx.x * blockDim.x;
    if (k < 512) {
        const float* r = cb + (size_t)k * 64;
        float s = 0.f; double sd = 0.0;
        for (int d = 0; d < 64; ++d) {
            s = fmaf(r[d], r[d], s);
            sd += (double)r[d] * (double)r[d];
        }
        csqf[k] = s; csqd[k] = sd;
    }
}

// ---------------- border codeword ----------------
__global__ void borderK(const double* __restrict__ csqd, int* __restrict__ kborder,
                        int* __restrict__ counts, double* __restrict__ lossAcc) {
    __shared__ double sV[512];
    __shared__ int sI[512];
    const int t = threadIdx.x;
    sV[t] = csqd[t]; sI[t] = t;
    __syncthreads();
    for (int st = 256; st > 0; st >>= 1) {
        if (t < st) {
            double v2 = sV[t + st]; int i2 = sI[t + st];
            if (v2 < sV[t] || (v2 == sV[t] && i2 < sI[t])) { sV[t] = v2; sI[t] = i2; }
        }
        __syncthreads();
    }
    if (t == 0) {
        int k = sI[0];
        *kborder = k;
        atomicAdd(&counts[k], 4224);
        atomicAdd(lossAcc, 4224.0 * sV[0]);
    }
}

// ---------------- fill symbols with border codeword ----------------
__global__ __launch_bounds__(256) void fillK(const int* __restrict__ kborder,
                                             const float* __restrict__ cb,
                                             float* __restrict__ out) {
    const int kb = *kborder;
    int E = blockIdx.x * 256 + threadIdx.x;
    if (E < SYM_N) {
        int d = (E / HW2) & 63;
        out[E] = cb[(size_t)kb * 64 + d];
    }
}

// ---------------- legacy conv 4x4 s2 (tier2 fallback conv1) ----------------
template<int CIN, int COUT, int IH, int IW, bool BN_IN, bool STORE, bool STATS,
         typename TI, typename TO>
__global__ __launch_bounds__(256) void conv4x4s2K(
    const TI* __restrict__ in, const float* __restrict__ wgt,
    const float* __restrict__ bias,
    const float* __restrict__ inScale, const float* __restrict__ inShift,
    TO* __restrict__ out, double* __restrict__ gSum, double* __restrict__ gSq)
{
    constexpr int OH = IH / 2, OW = IW / 2;
    constexpr int COLB = OW / 16;
    __shared__ float sIn[8 * 18 * 34];
    __shared__ float sW[128 * 64];
    __shared__ float sStat[128];

    const int tid = threadIdx.x;
    const int tx = tid & 15, ty = tid >> 4;
    const int cog = ty & 7, rg = ty >> 3;
    const int n = blockIdx.z;
    const int coBase = blockIdx.y * 64;
    const int brow = blockIdx.x / COLB, bcol = blockIdx.x % COLB;
    const int oh0 = brow * 8, ow0 = bcol * 16;
    const int ihb = oh0 * 2 - 1, iwb = ow0 * 2 - 1;

    float acc[8][4];
#pragma unroll
    for (int j = 0; j < 8; ++j)
#pragma unroll
        for (int r = 0; r < 4; ++r) acc[j][r] = 0.f;

    for (int c0 = 0; c0 < CIN; c0 += 8) {
        const int CC = (CIN - c0 < 8) ? (CIN - c0) : 8;
        for (int i = tid; i < 8 * 18 * 34; i += 256) {
            int ci = i / 612; int rem = i - ci * 612;
            int ih = rem / 34; int iw = rem - ih * 34;
            float v = 0.f;
            int gh = ihb + ih, gw = iwb + iw;
            if (ci < CC && (unsigned)gh < (unsigned)IH && (unsigned)gw < (unsigned)IW) {
                float r0 = ldv(&in[(((size_t)n * CIN + (c0 + ci)) * IH + gh) * IW + gw]);
                if (BN_IN) r0 = fmaxf(fmaf(r0, inScale[c0 + ci], inShift[c0 + ci]), 0.f);
                v = r0;
            }
            sIn[i] = v;
        }
        for (int i = tid; i < 8192; i += 256) {
            int co = i >> 7, r = i & 127;
            int ci = r >> 4, t = r & 15;
            float v = 0.f;
            if (ci < CC) v = wgt[(((size_t)(coBase + co)) * CIN + (c0 + ci)) * 16 + t];
            sW[r * 64 + (co ^ ((r & 7) << 3))] = v;
        }
        __syncthreads();
        for (int ci = 0; ci < CC; ++ci) {
#pragma unroll
            for (int kh = 0; kh < 4; ++kh) {
#pragma unroll
                for (int kw = 0; kw < 4; ++kw) {
                    const int tap = kh * 4 + kw;
                    const float* wp = sW + (ci * 16 + tap) * 64 + ((cog * 8) ^ ((tap & 7) << 3));
                    float4 wa = *(const float4*)wp;
                    float4 wb = *(const float4*)(wp + 4);
                    const float* ip = sIn + (ci * 18 + rg * 8 + kh) * 34 + tx * 2 + kw;
                    float wv[8] = {wa.x, wa.y, wa.z, wa.w, wb.x, wb.y, wb.z, wb.w};
                    float iv[4] = {ip[0], ip[68], ip[136], ip[204]};
#pragma unroll
                    for (int j = 0; j < 8; ++j)
#pragma unroll
                        for (int r = 0; r < 4; ++r)
                            acc[j][r] = fmaf(wv[j], iv[r], acc[j][r]);
                }
            }
        }
        __syncthreads();
    }

    if (STATS) {
        if (tid < 128) sStat[tid] = 0.f;
        __syncthreads();
    }

    const int coG = coBase + cog * 8;
#pragma unroll
    for (int j = 0; j < 8; ++j) {
        float bv = bias[coG + j];
        float s = 0.f, s2 = 0.f;
#pragma unroll
        for (int r = 0; r < 4; ++r) {
            float v = acc[j][r] + bv;
            if (STORE)
                stv(&out[(((size_t)n * COUT + coG + j) * OH + (oh0 + rg * 4 + r)) * OW + ow0 + tx], v);
            s += v; s2 = fmaf(v, v, s2);
        }
        if (STATS) {
#pragma unroll
            for (int m = 1; m < 16; m <<= 1) {
                s  += __shfl_xor(s, m, 64);
                s2 += __shfl_xor(s2, m, 64);
            }
            if (tx == 0) {
                atomicAdd(&sStat[cog * 8 + j], s);
                atomicAdd(&sStat[64 + cog * 8 + j], s2);
            }
        }
    }
    if (STATS) {
        __syncthreads();
        if (tid < 64) {
            atomicAdd(&gSum[coBase + tid], (double)sStat[tid]);
            atomicAdd(&gSq[coBase + tid],  (double)sStat[64 + tid]);
        }
    }
}

// ---------------- conv 4x4 s2, 8co x 8px tile (conv1 primary + tier2) --------
template<int CIN, int COUT, int IH, int IW, int TH, int TW, bool BN_IN,
         bool STORE, bool STATS, typename TI, typename TO>
__global__ __launch_bounds__(256, 3) void conv8K(
    const TI* __restrict__ in, const float* __restrict__ wgt,
    const float* __restrict__ bias,
    const float* __restrict__ inScale, const float* __restrict__ inShift,
    TO* __restrict__ out, double* __restrict__ gSum, double* __restrict__ gSq)
{
    constexpr int OH = IH / 2, OW = IW / 2;
    constexpr int COLB = OW / TW;
    constexpr int SW = TW / 2;
    constexpr int ITH = TH * 2 + 2;
    constexpr int ITWP = TW * 2 + 4;
    constexpr int INSZ = 4 * ITH * ITWP;

    __shared__ float sIn[INSZ];
    __shared__ float sW[4 * 16 * 64];
    __shared__ float sStat[128];

    const int tid = threadIdx.x;
    const int s = tid & 31, cog = tid >> 5;
    const int sw = s & (SW - 1), sh = s / SW;
    const int n = blockIdx.z;
    const int coBase = blockIdx.y * 64;
    const int brow = blockIdx.x / COLB, bcol = blockIdx.x % COLB;
    const int oh0 = brow * TH, ow0 = bcol * TW;
    const int ihb = oh0 * 2 - 1, iwb = ow0 * 2 - 1;

    float acc[8][8];
#pragma unroll
    for (int c = 0; c < 8; ++c)
#pragma unroll
        for (int p = 0; p < 8; ++p) acc[c][p] = 0.f;

    for (int c0 = 0; c0 < CIN; c0 += 4) {
        const int CC = (CIN - c0 < 4) ? (CIN - c0) : 4;
        for (int i = tid; i < INSZ; i += 256) {
            int ci = i / (ITH * ITWP); int rem = i - ci * (ITH * ITWP);
            int ih = rem / ITWP; int iw = rem - ih * ITWP;
            float v = 0.f;
            int gh = ihb + ih, gw = iwb + iw;
            if (ci < CC && (unsigned)gh < (unsigned)IH && (unsigned)gw < (unsigned)IW) {
                float r0 = ldv(&in[(((size_t)n * CIN + (c0 + ci)) * IH + gh) * IW + gw]);
                if (BN_IN) r0 = fmaxf(fmaf(r0, inScale[c0 + ci], inShift[c0 + ci]), 0.f);
                v = r0;
            }
            sIn[i] = v;
        }
        for (int i = tid; i < 4096; i += 256) {
            int r = i >> 6, co = i & 63;
            int ci = r >> 4, tap = r & 15;
            float v = (ci < CC) ? wgt[(((size_t)(coBase + co)) * CIN + (c0 + ci)) * 16 + tap] : 0.f;
            sW[r * 64 + co] = v;
        }
        __syncthreads();
        for (int ci = 0; ci < CC; ++ci) {
#pragma unroll
            for (int kh = 0; kh < 4; ++kh) {
                float inv[4][8];
#pragma unroll
                for (int r = 0; r < 4; ++r) {
                    const float* ip = sIn + (ci * ITH + (sh * 4 + r) * 2 + kh) * ITWP + sw * 4;
                    float4 a = *(const float4*)ip;
                    float4 b = *(const float4*)(ip + 4);
                    inv[r][0] = a.x; inv[r][1] = a.y; inv[r][2] = a.z; inv[r][3] = a.w;
                    inv[r][4] = b.x; inv[r][5] = b.y; inv[r][6] = b.z; inv[r][7] = b.w;
                }
#pragma unroll
                for (int kw = 0; kw < 4; ++kw) {
                    const float* wp = sW + (ci * 16 + kh * 4 + kw) * 64 + cog * 8;
                    float4 wa = *(const float4*)wp;
                    float4 wb = *(const float4*)(wp + 4);
                    float wv[8] = {wa.x, wa.y, wa.z, wa.w, wb.x, wb.y, wb.z, wb.w};
#pragma unroll
                    for (int c = 0; c < 8; ++c)
#pragma unroll
                        for (int r = 0; r < 4; ++r)
#pragma unroll
                            for (int j = 0; j < 2; ++j)
                                acc[c][r * 2 + j] =
                                    fmaf(wv[c], inv[r][2 * j + kw], acc[c][r * 2 + j]);
                }
            }
        }
        __syncthreads();
    }

    if (STATS) {
        if (tid < 128) sStat[tid] = 0.f;
        __syncthreads();
    }

    const int coG = coBase + cog * 8;
#pragma unroll
    for (int c = 0; c < 8; ++c) {
        float bv = bias[coG + c];
        float s1 = 0.f, s2 = 0.f;
#pragma unroll
        for (int p = 0; p < 8; ++p) {
            float v = acc[c][p] + bv;
            int oh = oh0 + sh * 4 + (p >> 1), ow = ow0 + sw * 2 + (p & 1);
            if (STORE)
                stv(&out[(((size_t)n * COUT + coG + c) * OH + oh) * OW + ow], v);
            s1 += v; s2 = fmaf(v, v, s2);
        }
        if (STATS) {
#pragma unroll
            for (int m = 1; m < 32; m <<= 1) {
                s1 += __shfl_xor(s1, m, 64);
                s2 += __shfl_xor(s2, m, 64);
            }
            if ((tid & 31) == 0) {
                atomicAdd(&sStat[cog * 8 + c], s1);
                atomicAdd(&sStat[64 + cog * 8 + c], s2);
            }
        }
    }
    if (STATS) {
        __syncthreads();
        if (tid < 64) {
            atomicAdd(&gSum[coBase + tid], (double)sStat[tid]);
            atomicAdd(&gSq[coBase + tid],  (double)sStat[64 + tid]);
        }
    }
}

// ---------------- BN finalize ----------------
__global__ void bnFinK(const double* __restrict__ gSum, const double* __restrict__ gSq,
                       const float* __restrict__ g, const float* __restrict__ be,
                       float* __restrict__ scale, float* __restrict__ shift,
                       int C, double cnt)
{
    int c = threadIdx.x;
    if (c < C) {
        double m = gSum[c] / cnt;
        double v = gSq[c] / cnt - m * m;
        double sc = (double)g[c] / sqrt(v + 1e-5);
        scale[c] = (float)sc;
        shift[c] = (float)((double)be[c] - m * sc);
    }
}

// ---------------- weight repack: [co][ci][tap] f32 -> [tap][chunk][co][16] f16 ----
__global__ __launch_bounds__(256) void splitWK(
    const float* __restrict__ w, _Float16* __restrict__ wsOut, int CIN, int COUT)
{
    int CH = CIN >> 4;
    int total = 16 * CH * COUT * 16;
    for (int i = blockIdx.x * 256 + threadIdx.x; i < total; i += gridDim.x * 256) {
        int cil = i & 15; int r = i >> 4;
        int co = r % COUT; r /= COUT;
        int c = r % CH; int tap = r / CH;
        int ci = c * 16 + cil;
        wsOut[i] = (_Float16)w[((size_t)co * CIN + ci) * 16 + tap];
    }
}

// ---------------- MFMA conv 4x4 s2 (implicit GEMM per tap) ----------------
template<int CIN, int COUT, int IH, int NF, bool BN_IN, typename TO>
__global__ __launch_bounds__(512) void convMfmaK(
    const _Float16* __restrict__ in, const _Float16* __restrict__ wsplit,
    const float* __restrict__ bias,
    const float* __restrict__ inScale, const float* __restrict__ inShift,
    TO* __restrict__ out, double* __restrict__ gSum, double* __restrict__ gSq)
{
    constexpr int OH = IH / 2;
    constexpr int OWB = OH / 32;
    constexpr int CH = CIN / 16;
    __shared__ _Float16 sA[10 * 68 * 24];
    __shared__ float sStat[2 * COUT];

    const int tid = threadIdx.x;
    const int l = tid & 63, wid = tid >> 6;
    const int lane31 = l & 31, hs = l >> 5;
    const int mw = wid & 3, nw = wid >> 2;
    const int n = blockIdx.z;
    const int ohB = (blockIdx.x / OWB) * 4;
    const int owB = (blockIdx.x % OWB) * 32;
    const int ghBase = 2 * ohB - 1, gwBase = 2 * owB - 1;

    for (int i = tid; i < 2 * COUT; i += 512) sStat[i] = 0.f;

    f32x16 acc[NF];
#pragma unroll
    for (int f = 0; f < NF; ++f)
#pragma unroll
        for (int j = 0; j < 16; ++j) acc[f][j] = 0.f;

    for (int c = 0; c < CH; ++c) {
        __syncthreads();
        for (int i = tid; i < 10 * 68 * 16; i += 512) {
            int iw = i % 68; int r = i / 68; int ih = r % 10; int cil = r / 10;
            int gh = ghBase + ih, gw = gwBase + iw;
            float v = 0.f;
            if ((unsigned)gh < (unsigned)IH && (unsigned)gw < (unsigned)IH) {
                v = (float)in[(((size_t)n * CIN + c * 16 + cil) * IH + gh) * IH + gw];
                if (BN_IN) v = fmaxf(fmaf(v, inScale[c * 16 + cil], inShift[c * 16 + cil]), 0.f);
            }
            sA[(ih * 68 + iw) * 24 + cil] = (_Float16)v;
        }
        __syncthreads();
#pragma unroll
        for (int kh = 0; kh < 4; ++kh) {
#pragma unroll
            for (int kw = 0; kw < 4; ++kw) {
                const int ihX = 2 * mw + kh;
                half8 a = *(const half8*)&sA[(ihX * 68 + 2 * lane31 + kw) * 24 + hs * 8];
                const _Float16* bp = wsplit
                    + (((size_t)(kh * 4 + kw) * CH + c) * COUT + nw * (NF * 32) + lane31) * 16
                    + hs * 8;
#pragma unroll
                for (int f = 0; f < NF; ++f) {
                    half8 b = *(const half8*)(bp + (size_t)f * 32 * 16);
                    acc[f] = __builtin_amdgcn_mfma_f32_32x32x16_f16(a, b, acc[f], 0, 0, 0);
                }
            }
        }
    }

    const int oh = ohB + mw;
#pragma unroll
    for (int f = 0; f < NF; ++f) {
        int co = nw * (NF * 32) + f * 32 + lane31;
        float bv = bias[co];
        float s1 = 0.f, s2 = 0.f;
#pragma unroll
        for (int q = 0; q < 4; ++q) {
            float v0 = acc[f][q * 4 + 0] + bv;
            float v1 = acc[f][q * 4 + 1] + bv;
            float v2 = acc[f][q * 4 + 2] + bv;
            float v3 = acc[f][q * 4 + 3] + bv;
            s1 += (v0 + v1) + (v2 + v3);
            s2 = fmaf(v0, v0, s2); s2 = fmaf(v1, v1, s2);
            s2 = fmaf(v2, v2, s2); s2 = fmaf(v3, v3, s2);
            int ow = owB + q * 8 + hs * 4;
            st4(&out[(((size_t)n * COUT + co) * OH + oh) * OH + ow], v0, v1, v2, v3);
        }
        s1 += __shfl_xor(s1, 32, 64);
        s2 += __shfl_xor(s2, 32, 64);
        if (hs == 0) {
            atomicAdd(&sStat[co], s1);
            atomicAdd(&sStat[COUT + co], s2);
        }
    }
    __syncthreads();
    for (int i = tid; i < COUT; i += 512) {
        atomicAdd(&gSum[i], (double)sStat[i]);
        atomicAdd(&gSq[i],  (double)sStat[COUT + i]);
    }
}

// ---------------- fused head: 1x1 conv (BN3+ReLU) + VQ, per 64-px block ------
// 256 thr = 4 waves. Phase A: wave w computes partial z over channels
// [64w,64w+64) for its 64 px (wq staged fp16 in LDS); LDS-atomic reduce.
// Phase B: wave w scans codebook quarter [128w,128w+128); cross-wave argmin.
__global__ __launch_bounds__(256) void headK(
    const float* __restrict__ y3, const float* __restrict__ wq,
    const float* __restrict__ bq,
    const float* __restrict__ sc3, const float* __restrict__ sh3,
    const float* __restrict__ cb, const float* __restrict__ csqf,
    float* __restrict__ out, int* __restrict__ counts,
    double* __restrict__ lossAcc)
{
    __shared__ _Float16 sWq[256 * 64];   // 32 KB  [c][d]
    __shared__ float sZ[64 * 66];        // 16.9 KB
    __shared__ float sS[256], sH[256], sBq[64];
    __shared__ float sB[256];
    __shared__ int   sI[256];

    const int tid = threadIdx.x;
    const int l = tid & 63, w = tid >> 6;
    const int px = blockIdx.x * 64 + l;
    const int n = px >> 10, hw = px & 1023;

    // stage wq (transpose + fp16), bn consts, zero sZ
    for (int i = tid; i < 16384; i += 256)
        sWq[i] = (_Float16)wq[(size_t)(i & 63) * 256 + (i >> 6)];
    if (tid < 256) { sS[tid] = sc3[tid]; sH[tid] = sh3[tid]; }
    if (tid < 64) sBq[tid] = bq[tid];
    for (int i = tid; i < 64 * 66; i += 256) sZ[i] = 0.f;
    __syncthreads();

    // ---- phase A: partial 1x1 conv over this wave's channel quarter ----
    float accv[64];
#pragma unroll
    for (int d = 0; d < 64; ++d) accv[d] = 0.f;
    const float* base = y3 + (((size_t)n * 256 + 64 * w) << 10) + hw;
    for (int c = 0; c < 64; ++c) {
        int cg = 64 * w + c;
        float h = base[(size_t)c << 10];
        h = fmaxf(fmaf(h, sS[cg], sH[cg]), 0.f);
        const _Float16* wrow = sWq + cg * 64;
#pragma unroll
        for (int j = 0; j < 8; ++j) {
            half8 w8 = *(const half8*)(wrow + 8 * j);
#pragma unroll
            for (int e = 0; e < 8; ++e)
                accv[8 * j + e] = fmaf(h, (float)w8[e], accv[8 * j + e]);
        }
    }
#pragma unroll
    for (int d = 0; d < 64; ++d) atomicAdd(&sZ[l * 66 + d], accv[d]);
    __syncthreads();

    // ---- phase B: VQ scan over this wave's codebook quarter ----
    float zr[64];
#pragma unroll
    for (int d = 0; d < 64; ++d) zr[d] = sZ[l * 66 + d] + sBq[d];

    const int kbase = w * 128;
    float best = 3.4e38f; int bidx = kbase;
    for (int kk = 0; kk < 128; ++kk) {
        const float4* crow = (const float4*)(cb + (size_t)(kbase + kk) * 64);
        float d0 = 0.f, d1 = 0.f, d2 = 0.f, d3 = 0.f;
#pragma unroll
        for (int q = 0; q < 16; ++q) {
            float4 c4 = crow[q];
            d0 = fmaf(zr[4*q+0], c4.x, d0);
            d1 = fmaf(zr[4*q+1], c4.y, d1);
            d2 = fmaf(zr[4*q+2], c4.z, d2);
            d3 = fmaf(zr[4*q+3], c4.w, d3);
        }
        float dot = (d0 + d1) + (d2 + d3);
        float score = csqf[kbase + kk] - 2.0f * dot;
        if (score < best) { best = score; bidx = kbase + kk; }
    }

    sB[tid] = best; sI[tid] = bidx;
    __syncthreads();
    if (w == 0) {
#pragma unroll
        for (int g = 1; g < 4; ++g) {
            float b = sB[l + 64 * g]; int i = sI[l + 64 * g];
            if (b < best || (b == best && i < bidx)) { best = b; bidx = i; }
        }
        atomicAdd(&counts[bidx], 1);

        const int hh = hw >> 5, ww = hw & 31;
        const int obase = n * CHW + (hh + 1) * 34 + (ww + 1);
        const float4* qp = (const float4*)(cb + (size_t)bidx * 64);
        float sq = 0.f;
#pragma unroll
        for (int q = 0; q < 16; ++q) {
            float4 c4 = qp[q];
            float vv[4] = {c4.x, c4.y, c4.z, c4.w};
#pragma unroll
            for (int j = 0; j < 4; ++j) {
                int d = 4 * q + j;
                float df = vv[j] - zr[d];
                sq = fmaf(df, df, sq);
                out[obase + d * HW2] = vv[j];
            }
        }
#pragma unroll
        for (int m = 1; m < 64; m <<= 1) sq += __shfl_xor(sq, m, 64);
        if (l == 0) atomicAdd(lossAcc, (double)sq);
    }
}

// ---------------- tier2: 1x1 conv kernel ----------------
__global__ __launch_bounds__(128) void convqK(
    const float* __restrict__ y3, const float* __restrict__ wq,
    const float* __restrict__ bq,
    const float* __restrict__ sc3, const float* __restrict__ sh3,
    float* __restrict__ z)
{
    __shared__ float sWq[64 * 68];
    __shared__ float sS[64], sH[64];
    const int tid = threadIdx.x;
    const int px = blockIdx.x * 128 + tid;
    const int n = px >> 10, hw = px & 1023;

    float accv[64];
#pragma unroll
    for (int d = 0; d < 64; ++d) accv[d] = 0.f;

    const float* base = y3 + (((size_t)n * 256) << 10) + hw;
    for (int c0 = 0; c0 < 256; c0 += 64) {
        __syncthreads();
        for (int i = tid; i < 4096; i += 128) {
            int c = i & 63, d = i >> 6;
            sWq[c * 68 + d] = wq[(size_t)d * 256 + c0 + c];
        }
        if (tid < 64) { sS[tid] = sc3[c0 + tid]; sH[tid] = sh3[c0 + tid]; }
        __syncthreads();
        for (int c = 0; c < 64; ++c) {
            float h = base[(size_t)(c0 + c) << 10];
            h = fmaxf(fmaf(h, sS[c], sH[c]), 0.f);
            const float4* wrow = (const float4*)(sWq + c * 68);
#pragma unroll
            for (int q = 0; q < 16; ++q) {
                float4 w4 = wrow[q];
                accv[4*q+0] = fmaf(h, w4.x, accv[4*q+0]);
                accv[4*q+1] = fmaf(h, w4.y, accv[4*q+1]);
                accv[4*q+2] = fmaf(h, w4.z, accv[4*q+2]);
                accv[4*q+3] = fmaf(h, w4.w, accv[4*q+3]);
            }
        }
    }
    float* zo = z + (size_t)px * 64;
    const float4* bq4 = (const float4*)bq;
#pragma unroll
    for (int q = 0; q < 16; ++q) {
        float4 b4 = bq4[q];
        float4 v;
        v.x = accv[4*q+0] + b4.x; v.y = accv[4*q+1] + b4.y;
        v.z = accv[4*q+2] + b4.z; v.w = accv[4*q+3] + b4.w;
        ((float4*)zo)[q] = v;
    }
}

// ---------------- tier2: vq kernel ----------------
__global__ __launch_bounds__(256) void vqK(
    const float* __restrict__ z, const float* __restrict__ cb,
    const float* __restrict__ csqf, float* __restrict__ out,
    int* __restrict__ counts, double* __restrict__ lossAcc)
{
    const int tid = threadIdx.x;
    const int lane = tid & 63;
    const int grp = tid >> 6;
    const int px = blockIdx.x * 64 + lane;

    float zr[64];
    const float4* zp = (const float4*)(z + (size_t)px * 64);
#pragma unroll
    for (int q = 0; q < 16; ++q) {
        float4 t = zp[q];
        zr[4*q] = t.x; zr[4*q+1] = t.y; zr[4*q+2] = t.z; zr[4*q+3] = t.w;
    }

    const int kbase = grp * 128;
    float best = 3.4e38f; int bidx = kbase;
    for (int kk = 0; kk < 128; ++kk) {
        const float4* crow = (const float4*)(cb + (size_t)(kbase + kk) * 64);
        float d0 = 0.f, d1 = 0.f, d2 = 0.f, d3 = 0.f;
#pragma unroll
        for (int q = 0; q < 16; ++q) {
            float4 c4 = crow[q];
            d0 = fmaf(zr[4*q+0], c4.x, d0);
            d1 = fmaf(zr[4*q+1], c4.y, d1);
            d2 = fmaf(zr[4*q+2], c4.z, d2);
            d3 = fmaf(zr[4*q+3], c4.w, d3);
        }
        float dot = (d0 + d1) + (d2 + d3);
        float score = csqf[kbase + kk] - 2.0f * dot;
        if (score < best) { best = score; bidx = kbase + kk; }
    }

    __shared__ float sB[256];
    __shared__ int   sI[256];
    sB[tid] = best; sI[tid] = bidx;
    __syncthreads();
    if (grp == 0) {
#pragma unroll
        for (int g = 1; g < 4; ++g) {
            float b = sB[lane + 64 * g]; int i = sI[lane + 64 * g];
            if (b < best || (b == best && i < bidx)) { best = b; bidx = i; }
        }
        atomicAdd(&counts[bidx], 1);

        const int n = px >> 10, hw = px & 1023;
        const int h = hw >> 5, w = hw & 31;
        const int obase = n * CHW + (h + 1) * 34 + (w + 1);
        const float4* qp = (const float4*)(cb + (size_t)bidx * 64);
        float sq = 0.f;
#pragma unroll
        for (int q = 0; q < 16; ++q) {
            float4 c4 = qp[q];
            float vv[4] = {c4.x, c4.y, c4.z, c4.w};
#pragma unroll
            for (int j = 0; j < 4; ++j) {
                int d = 4 * q + j;
                float df = vv[j] - zr[d];
                sq = fmaf(df, df, sq);
                out[obase + d * HW2] = vv[j];
            }
        }
#pragma unroll
        for (int m = 1; m < 64; m <<= 1) sq += __shfl_xor(sq, m, 64);
        if (lane == 0) atomicAdd(lossAcc, (double)sq);
    }
}

// ---------------- loss + perplexity ----------------
__global__ void finalizeK(const int* __restrict__ counts,
                          const double* __restrict__ lossAcc,
                          float* __restrict__ out)
{
    const int tid = threadIdx.x;
    double ent = 0.0;
    for (int k = tid; k < 512; k += 64) {
        double p = (double)counts[k] / NPX;
        ent -= p * log(p + 1e-10);
    }
#pragma unroll
    for (int m = 1; m < 64; m <<= 1) ent += __shfl_xor(ent, m, 64);
    if (tid == 0) {
        out[SYM_N]     = (float)(1.25 * lossAcc[0] / (double)SYM_N);
        out[SYM_N + 1] = (float)exp(ent);
    }
}

// ---------------- fallback: zero + sentinel ----------------
__global__ __launch_bounds__(256) void zeroOutK(float* __restrict__ out, int n) {
    int i = blockIdx.x * 256 + threadIdx.x;
    if (i < n) out[i] = 0.0f;
}
__global__ void sentinelK(float* out, float lossv, float perpv) {
    if (threadIdx.x == 0) { out[SYM_N] = lossv; out[SYM_N + 1] = perpv; }
}

// =======================================================================
// primary path
// =======================================================================
static void run_mfma(void* const* d_in, float* out, char* ws, hipStream_t stream)
{
    const float* x   = (const float*)d_in[0];
    const float* w1  = (const float*)d_in[1];
    const float* b1  = (const float*)d_in[2];
    const float* g1  = (const float*)d_in[3];
    const float* be1 = (const float*)d_in[4];
    const float* w2  = (const float*)d_in[5];
    const float* b2  = (const float*)d_in[6];
    const float* g2  = (const float*)d_in[7];
    const float* be2 = (const float*)d_in[8];
    const float* w3  = (const float*)d_in[9];
    const float* b3  = (const float*)d_in[10];
    const float* g3  = (const float*)d_in[11];
    const float* be3 = (const float*)d_in[12];
    const float* wq  = (const float*)d_in[13];
    const float* bq  = (const float*)d_in[14];
    const float* cb  = (const float*)d_in[15];

    double* statd  = (double*)(ws);
    float*  sscale = (float*)(ws + 16384);
    int*    counts = (int*)(ws + 24576);
    float*  csqf   = (float*)(ws + 28672);
    double* csqd   = (double*)(ws + 30720);
    int*    kbord  = (int*)(ws + 34816);
    double* lossAcc = statd + 1536;

    char* A0 = ws + 65536;
    _Float16* y1h = (_Float16*)A0;
    _Float16* y2h = (_Float16*)(A0 + 67108864ull);
    float*    y3  = (float*)(A0 + 100663296ull);
    _Float16* w2s = (_Float16*)(A0 + 142606336ull);
    _Float16* w3s = (_Float16*)(A0 + 142868480ull);

    initStatsK<<<7, 256, 0, stream>>>(statd, counts);
    csqK<<<2, 256, 0, stream>>>(cb, csqf, csqd);
    borderK<<<1, 512, 0, stream>>>(csqd, kbord, counts, lossAcc);
    fillK<<<(SYM_N + 255) / 256, 256, 0, stream>>>(kbord, cb, out);
    splitWK<<<512, 256, 0, stream>>>(w2, w2s, 64, 128);
    splitWK<<<2048, 256, 0, stream>>>(w3, w3s, 128, 256);

    conv8K<3, 64, 256, 256, 8, 32, false, true, true, float, _Float16>
        <<<dim3(64, 1, BATCH), 256, 0, stream>>>(
        x, w1, b1, nullptr, nullptr, y1h, statd + 0, statd + 256);
    bnFinK<<<1, 256, 0, stream>>>(statd + 0, statd + 256, g1, be1,
                                  sscale + 0, sscale + 256, 64, 524288.0);

    convMfmaK<64, 128, 128, 2, true, _Float16>
        <<<dim3(32, 1, BATCH), 512, 0, stream>>>(
        y1h, w2s, b2, sscale + 0, sscale + 256, y2h, statd + 512, statd + 768);
    bnFinK<<<1, 256, 0, stream>>>(statd + 512, statd + 768, g2, be2,
                                  sscale + 512, sscale + 768, 128, 131072.0);

    convMfmaK<128, 256, 64, 4, true, float>
        <<<dim3(8, 1, BATCH), 512, 0, stream>>>(
        y2h, w3s, b3, sscale + 512, sscale + 768, y3, statd + 1024, statd + 1280);
    bnFinK<<<1, 256, 0, stream>>>(statd + 1024, statd + 1280, g3, be3,
                                  sscale + 1024, sscale + 1280, 256, 32768.0);

    headK<<<512, 256, 0, stream>>>(y3, wq, bq, sscale + 1024, sscale + 1280,
                                   cb, csqf, out, counts, lossAcc);
    finalizeK<<<1, 64, 0, stream>>>(counts, lossAcc, out);
}

// =======================================================================
// fallback tier2: single-pass bf16 storage (proven structure)
// =======================================================================
static void run_fast_bf16(void* const* d_in, float* out, char* ws, hipStream_t stream)
{
    const float* x   = (const float*)d_in[0];
    const float* w1  = (const float*)d_in[1];
    const float* b1  = (const float*)d_in[2];
    const float* g1  = (const float*)d_in[3];
    const float* be1 = (const float*)d_in[4];
    const float* w2  = (const float*)d_in[5];
    const float* b2  = (const float*)d_in[6];
    const float* g2  = (const float*)d_in[7];
    const float* be2 = (const float*)d_in[8];
    const float* w3  = (const float*)d_in[9];
    const float* b3  = (const float*)d_in[10];
    const float* g3  = (const float*)d_in[11];
    const float* be3 = (const float*)d_in[12];
    const float* wq  = (const float*)d_in[13];
    const float* bq  = (const float*)d_in[14];
    const float* cb  = (const float*)d_in[15];

    double* statd  = (double*)(ws);
    float*  sscale = (float*)(ws + 16384);
    int*    counts = (int*)(ws + 24576);
    float*  csqf   = (float*)(ws + 28672);
    double* csqd   = (double*)(ws + 30720);
    int*    kbord  = (int*)(ws + 34816);
    double* lossAcc = statd + 1536;

    __hip_bfloat16* y1 = (__hip_bfloat16*)(ws + 65536);
    __hip_bfloat16* y2 = (__hip_bfloat16*)(ws + 65536 + 67108864ull);
    float* y3 = (float*)(ws + 65536);
    float* z  = (float*)(ws + 65536 + 33554432ull);

    initStatsK<<<7, 256, 0, stream>>>(statd, counts);
    csqK<<<2, 256, 0, stream>>>(cb, csqf, csqd);
    borderK<<<1, 512, 0, stream>>>(csqd, kbord, counts, lossAcc);
    fillK<<<(SYM_N + 255) / 256, 256, 0, stream>>>(kbord, cb, out);

    conv4x4s2K<3, 64, 256, 256, false, true, true, float, __hip_bfloat16>
        <<<dim3(128, 1, BATCH), 256, 0, stream>>>(
        x, w1, b1, nullptr, nullptr, y1, statd + 0, statd + 256);
    bnFinK<<<1, 256, 0, stream>>>(statd + 0, statd + 256, g1, be1,
                                  sscale + 0, sscale + 256, 64, 524288.0);

    conv8K<64, 128, 128, 128, 8, 32, true, true, true, __hip_bfloat16, __hip_bfloat16>
        <<<dim3(16, 2, BATCH), 256, 0, stream>>>(
        y1, w2, b2, sscale + 0, sscale + 256, y2, statd + 512, statd + 768);
    bnFinK<<<1, 256, 0, stream>>>(statd + 512, statd + 768, g2, be2,
                                  sscale + 512, sscale + 768, 128, 131072.0);

    conv8K<128, 256, 64, 64, 16, 16, true, true, true, __hip_bfloat16, float>
        <<<dim3(4, 4, BATCH), 256, 0, stream>>>(
        y2, w3, b3, sscale + 512, sscale + 768, y3, statd + 1024, statd + 1280);
    bnFinK<<<1, 256, 0, stream>>>(statd + 1024, statd + 1280, g3, be3,
                                  sscale + 1024, sscale + 1280, 256, 32768.0);

    convqK<<<256, 128, 0, stream>>>(y3, wq, bq, sscale + 1024, sscale + 1280, z);
    vqK<<<512, 256, 0, stream>>>(z, cb, csqf, out, counts, lossAcc);
    finalizeK<<<1, 64, 0, stream>>>(counts, lossAcc, out);
}

extern "C" void kernel_launch(void* const* d_in, const int* in_sizes, int n_in,
                              void* d_out, int out_size, void* d_ws, size_t ws_size,
                              hipStream_t stream)
{
    float* out = (float*)d_out;
    char* ws = (char*)d_ws;

    if (ws_size >= NEED1) {
        run_mfma(d_in, out, ws, stream);
    } else if (ws_size >= NEED2) {
        run_fast_bf16(d_in, out, ws, stream);
    } else {
        zeroOutK<<<(SYM_N + 2 + 255) / 256, 256, 0, stream>>>(out, SYM_N + 2);
        sentinelK<<<1, 64, 0, stream>>>(out, -4444.0f, -5555.0f);
    }
}